// Round 6
// baseline (473.826 us; speedup 1.0000x reference)
//
#include <hip/hip_runtime.h>
#include <hip/hip_bf16.h>

// Problem constants (Mp_encoder): N nodes, D dims, P metapaths.
constexpr int N = 4096;
constexpr int D = 256;
constexpr int P = 3;
constexpr int MAXDEG = 17;       // K+1
constexpr float TAU = 0.8f;
constexpr float MARGIN = 0.1f;
constexpr float EPS_PD = 1e-6f;

constexpr int LDP = 40;          // LDS k-stride for 64-tiles (2-way max conflicts)

// bf16 conversion-area offsets (elements), all 256-aligned
constexpr int OFF_ATTW = 1245184;       // 65536
constexpr int OFF_W1   = 1310720;       // 65536
constexpr int OFF_W2   = 1376256;       // 65536
constexpr int OFF_BG   = 1441792;       // 768
constexpr int OFF_ATTB = 1442560;       // 256
constexpr int OFF_AV   = 1442816;       // 256
constexpr int OFF_PA   = 1443072;       // 3 (reserve 256)
constexpr int OFF_B1   = 1443328;       // 256
constexpr int OFF_B2   = 1443584;       // 256
constexpr int CONV_TOTAL = 1443840;

typedef __attribute__((ext_vector_type(8))) short bfrag8;
typedef __attribute__((ext_vector_type(4))) float facc4;

__device__ inline facc4 mfma16(bfrag8 a, bfrag8 b, facc4 c) {
    return __builtin_amdgcn_mfma_f32_16x16x32_bf16(a, b, c, 0, 0, 0);
}
__device__ inline float b2f(__hip_bfloat16 v) { return __bfloat162float(v); }
__device__ inline float bfbits2f(unsigned short u) {
    return __uint_as_float(((unsigned int)u) << 16);
}
__device__ inline unsigned short f2bfbits(float v) {
    __hip_bfloat16 t = __float2bfloat16(v);
    return *(unsigned short*)&t;
}
__device__ inline int get_bf(const int* __restrict__ counter) { return counter[0] > 100; }

__device__ inline float load_in(const void* p, size_t i, int bf) {
    return bf ? __bfloat162float(((const __hip_bfloat16*)p)[i])
              : ((const float*)p)[i];
}

// async global->LDS, 16 bytes per lane; dest = wave-uniform base + lane*16
__device__ __forceinline__ void gl_lds16(const __hip_bfloat16* g, __hip_bfloat16* l) {
    __builtin_amdgcn_global_load_lds(
        (const __attribute__((address_space(1))) unsigned int*)g,
        (__attribute__((address_space(3))) unsigned int*)l, 16, 0, 0);
}

// ---------------------------------------------------------------------------
// 0. dtype detection (atomicMax sentinel) + zero atomic-accumulator region.
// ---------------------------------------------------------------------------
__global__ void __launch_bounds__(256)
detect_dtype(const unsigned int* __restrict__ w, int nwords,
             int* __restrict__ counter,
             float* __restrict__ zbuf, int nz) {
    int t0 = blockIdx.x * blockDim.x + threadIdx.x;
    if (t0 < nz) zbuf[t0] = 0.f;
    int stride = gridDim.x * blockDim.x;
    int c = 0;
    for (int i = t0; i < nwords; i += stride) {
        unsigned int x = w[i];
        if ((x & 0xFFFF0000u) == 0u && x != 0u) c++;
    }
    for (int s = 32; s > 0; s >>= 1) c += __shfl_down(c, s);
    if ((threadIdx.x & 63) == 0 && c > 0) atomicMax(counter, 1 << 20);
}

// ---------------------------------------------------------------------------
// 1. FUSED stage2: one dispatch =
//    blocks [0,256):          triple-B GCN GEMM reading RAW h / W_gcn
//    blocks [256,256+P*N):    sparse extraction (per (p,n) row of mps)
//    blocks [256+P*N, +64):   convert small dense weights to bf16 staging
// ---------------------------------------------------------------------------
__global__ void __launch_bounds__(256)
stage2(const void* __restrict__ h, const void* __restrict__ wg,
       const void* __restrict__ mps,
       const void* attw, const void* w1, const void* w2,
       const void* bg, const void* attb, const void* av,
       const void* pa, const void* b1, const void* b2,
       const int* __restrict__ counter,
       __hip_bfloat16* __restrict__ conv,
       __hip_bfloat16* __restrict__ xbuf,
       int* __restrict__ nbr_idx, float* __restrict__ nbr_val,
       int* __restrict__ neg_idx, int* __restrict__ deg) {
    __shared__ __align__(16) __hip_bfloat16 As[64 * LDP];
    __shared__ __align__(16) __hip_bfloat16 Bs[3][64 * LDP];
    int bid = blockIdx.x;
    int bf = get_bf(counter);
    if (bid < 256) {
        // ---- triple GEMM: X[z] = h @ Wg[z]^T, raw-input in-register convert
        int bm = (bid & 63) * 64, bn = (bid >> 6) * 64;
        int tid = threadIdx.x, wave = tid >> 6, lane = tid & 63;
        int quad = lane >> 4, l15 = lane & 15;
        int wr = (wave & 1) * 32, wc = (wave >> 1) * 32;
        facc4 acc[3][2][2] = {};
        int sr = tid >> 2, kq = (tid & 3) * 8;
        for (int k0 = 0; k0 < D; k0 += 32) {
            if (bf) {
                *(bfrag8*)&As[sr * LDP + kq] =
                    *(const bfrag8*)((const unsigned short*)h + (size_t)(bm + sr) * D + k0 + kq);
                #pragma unroll
                for (int z = 0; z < 3; z++)
                    *(bfrag8*)&Bs[z][sr * LDP + kq] =
                        *(const bfrag8*)((const unsigned short*)wg +
                                         (size_t)z * D * D + (size_t)(bn + sr) * D + k0 + kq);
            } else {
                const float* hp = (const float*)h + (size_t)(bm + sr) * D + k0 + kq;
                float4 a0 = *(const float4*)hp, a1 = *(const float4*)(hp + 4);
                bfrag8 t;
                t[0] = f2bfbits(a0.x); t[1] = f2bfbits(a0.y);
                t[2] = f2bfbits(a0.z); t[3] = f2bfbits(a0.w);
                t[4] = f2bfbits(a1.x); t[5] = f2bfbits(a1.y);
                t[6] = f2bfbits(a1.z); t[7] = f2bfbits(a1.w);
                *(bfrag8*)&As[sr * LDP + kq] = t;
                #pragma unroll
                for (int z = 0; z < 3; z++) {
                    const float* wp = (const float*)wg +
                        (size_t)z * D * D + (size_t)(bn + sr) * D + k0 + kq;
                    float4 b0 = *(const float4*)wp, b1v = *(const float4*)(wp + 4);
                    bfrag8 u;
                    u[0] = f2bfbits(b0.x);  u[1] = f2bfbits(b0.y);
                    u[2] = f2bfbits(b0.z);  u[3] = f2bfbits(b0.w);
                    u[4] = f2bfbits(b1v.x); u[5] = f2bfbits(b1v.y);
                    u[6] = f2bfbits(b1v.z); u[7] = f2bfbits(b1v.w);
                    *(bfrag8*)&Bs[z][sr * LDP + kq] = u;
                }
            }
            __syncthreads();
            bfrag8 af[2];
            #pragma unroll
            for (int mi = 0; mi < 2; mi++)
                af[mi] = *(const bfrag8*)&As[(wr + mi * 16 + l15) * LDP + quad * 8];
            #pragma unroll
            for (int z = 0; z < 3; z++) {
                bfrag8 bfr[2];
                #pragma unroll
                for (int ni = 0; ni < 2; ni++)
                    bfr[ni] = *(const bfrag8*)&Bs[z][(wc + ni * 16 + l15) * LDP + quad * 8];
                #pragma unroll
                for (int mi = 0; mi < 2; mi++)
                    #pragma unroll
                    for (int ni = 0; ni < 2; ni++)
                        acc[z][mi][ni] = mfma16(af[mi], bfr[ni], acc[z][mi][ni]);
            }
            __syncthreads();
        }
        #pragma unroll
        for (int z = 0; z < 3; z++)
            #pragma unroll
            for (int mi = 0; mi < 2; mi++)
                #pragma unroll
                for (int ni = 0; ni < 2; ni++) {
                    int col = bn + wc + ni * 16 + l15;
                    #pragma unroll
                    for (int r = 0; r < 4; r++) {
                        int row = bm + wr + mi * 16 + quad * 4 + r;
                        xbuf[(size_t)z * N * D + (size_t)row * D + col] =
                            __float2bfloat16(acc[z][mi][ni][r]);
                    }
                }
    } else if (bid < 256 + P * N) {
        // ---- sparse extraction for row (p,n); LDS aliased onto As
        int row = bid - 256;
        int t = threadIdx.x;
        int* cnt = (int*)As;
        int* sidx = ((int*)As) + 1;
        float* sval = (float*)(((int*)As) + 33);
        if (t == 0) *cnt = 0;
        __syncthreads();
        int e0 = t * 16;
        if (bf) {
            const uint4* base = (const uint4*)((const __hip_bfloat16*)mps + (size_t)row * N + e0);
            #pragma unroll
            for (int v = 0; v < 2; v++) {
                uint4 w = base[v];
                unsigned int ws[4] = {w.x, w.y, w.z, w.w};
                #pragma unroll
                for (int j = 0; j < 4; j++) {
                    unsigned short lo = (unsigned short)(ws[j] & 0xFFFFu);
                    unsigned short hi = (unsigned short)(ws[j] >> 16);
                    if (lo) { int k = atomicAdd(cnt, 1); if (k < 32) { sidx[k] = e0 + v * 8 + j * 2;     sval[k] = bfbits2f(lo); } }
                    if (hi) { int k = atomicAdd(cnt, 1); if (k < 32) { sidx[k] = e0 + v * 8 + j * 2 + 1; sval[k] = bfbits2f(hi); } }
                }
            }
        } else {
            const float4* base = (const float4*)((const float*)mps + (size_t)row * N + e0);
            #pragma unroll
            for (int v = 0; v < 4; v++) {
                float4 w = base[v];
                float ws[4] = {w.x, w.y, w.z, w.w};
                #pragma unroll
                for (int j = 0; j < 4; j++)
                    if (ws[j] > 0.f) { int k = atomicAdd(cnt, 1); if (k < 32) { sidx[k] = e0 + v * 4 + j; sval[k] = ws[j]; } }
            }
        }
        __syncthreads();
        if (t < 64) {
            int dg = *cnt; if (dg > MAXDEG) dg = MAXDEG;
            int myidx = 0; float myval = 0.f; int rank = 0;
            if (t < dg) {
                myidx = sidx[t]; myval = sval[t];
                for (int j = 0; j < dg; j++) rank += (sidx[j] < myidx) ? 1 : 0;
            }
            if (t < dg) { sidx[rank] = myidx; sval[rank] = myval; }
            if (t < MAXDEG) {
                nbr_idx[(size_t)row * MAXDEG + t] = (t < dg) ? sidx[t] : 0;
                nbr_val[(size_t)row * MAXDEG + t] = (t < dg) ? sval[t] : 0.f;
            }
            if (t == 0) deg[row] = dg;
            int c = t;
            bool cand = (c < dg + MAXDEG);
            bool isnbr = false;
            if (cand) for (int j = 0; j < dg; j++) isnbr |= (sidx[j] == c);
            bool nonnbr = cand && !isnbr;
            unsigned long long m = __ballot(nonnbr);
            int nrank = __popcll(m & ((c < 64) ? ((1ull << c) - 1ull) : ~0ull));
            if (nonnbr && nrank < MAXDEG) neg_idx[(size_t)row * MAXDEG + nrank] = c;
        }
    } else {
        // ---- convert small dense weights (h/W_gcn no longer staged)
        int cb = bid - (256 + P * N);
        const void* srcs[9] = {attw, w1, w2, bg, attb, av, pa, b1, b2};
        const int offs[9] = {OFF_ATTW, OFF_W1, OFF_W2, OFF_BG, OFF_ATTB,
                             OFF_AV, OFF_PA, OFF_B1, OFF_B2};
        const int lens[9] = {65536, 65536, 65536, 768, 256, 256, 3, 256, 256};
        int stride = 64 * 256;
        int t0 = cb * 256 + threadIdx.x;
        #pragma unroll
        for (int s = 0; s < 9; s++) {
            for (int i = t0; i < lens[s]; i += stride)
                conv[offs[s] + i] = __float2bfloat16(load_in(srcs[s], i, bf));
        }
    }
}

// ---------------------------------------------------------------------------
// 2. spmm + prelu: wave per node, idx/val in lane registers, 4-way unroll.
// ---------------------------------------------------------------------------
__global__ void __launch_bounds__(256)
spmm_prelu(const __hip_bfloat16* __restrict__ Xbase,
           const int* __restrict__ nbr_idx, const float* __restrict__ nbr_val,
           const int* __restrict__ deg, const __hip_bfloat16* __restrict__ conv,
           __hip_bfloat16* __restrict__ embBase) {
    int z = blockIdx.z;
    int wave = threadIdx.x >> 6, lane = threadIdx.x & 63;
    int n = blockIdx.x * 4 + wave;
    const __hip_bfloat16* X = Xbase + (size_t)z * N * D;
    int dg = deg[z * N + n];
    int idxv = 0; float valv = 0.f;
    if (lane < MAXDEG) {
        idxv = nbr_idx[((size_t)z * N + n) * MAXDEG + lane];
        valv = nbr_val[((size_t)z * N + n) * MAXDEG + lane];
    }
    float acc[4] = {0.f, 0.f, 0.f, 0.f};
    int k = 0;
    for (; k + 3 < dg; k += 4) {
        int j0 = __shfl(idxv, k), j1 = __shfl(idxv, k + 1);
        int j2 = __shfl(idxv, k + 2), j3 = __shfl(idxv, k + 3);
        float v0 = __shfl(valv, k), v1 = __shfl(valv, k + 1);
        float v2 = __shfl(valv, k + 2), v3 = __shfl(valv, k + 3);
        ushort4 x0 = *(const ushort4*)&X[(size_t)j0 * D + lane * 4];
        ushort4 x1 = *(const ushort4*)&X[(size_t)j1 * D + lane * 4];
        ushort4 x2 = *(const ushort4*)&X[(size_t)j2 * D + lane * 4];
        ushort4 x3 = *(const ushort4*)&X[(size_t)j3 * D + lane * 4];
        acc[0] += v0 * bfbits2f(x0.x) + v1 * bfbits2f(x1.x) + v2 * bfbits2f(x2.x) + v3 * bfbits2f(x3.x);
        acc[1] += v0 * bfbits2f(x0.y) + v1 * bfbits2f(x1.y) + v2 * bfbits2f(x2.y) + v3 * bfbits2f(x3.y);
        acc[2] += v0 * bfbits2f(x0.z) + v1 * bfbits2f(x1.z) + v2 * bfbits2f(x2.z) + v3 * bfbits2f(x3.z);
        acc[3] += v0 * bfbits2f(x0.w) + v1 * bfbits2f(x1.w) + v2 * bfbits2f(x2.w) + v3 * bfbits2f(x3.w);
    }
    for (; k < dg; k++) {
        int j0 = __shfl(idxv, k); float v0 = __shfl(valv, k);
        ushort4 x0 = *(const ushort4*)&X[(size_t)j0 * D + lane * 4];
        acc[0] += v0 * bfbits2f(x0.x); acc[1] += v0 * bfbits2f(x0.y);
        acc[2] += v0 * bfbits2f(x0.z); acc[3] += v0 * bfbits2f(x0.w);
    }
    ushort4 bb = *(const ushort4*)&conv[OFF_BG + z * D + lane * 4];
    float a = b2f(conv[OFF_PA + z]);
    ushort4 o;
    float v0 = acc[0] + bfbits2f(bb.x); o.x = f2bfbits(v0 > 0.f ? v0 : a * v0);
    float v1 = acc[1] + bfbits2f(bb.y); o.y = f2bfbits(v1 > 0.f ? v1 : a * v1);
    float v2 = acc[2] + bfbits2f(bb.z); o.z = f2bfbits(v2 > 0.f ? v2 : a * v2);
    float v3 = acc[3] + bfbits2f(bb.w); o.w = f2bfbits(v3 > 0.f ? v3 : a * v3);
    *(ushort4*)&embBase[(size_t)z * N * D + (size_t)n * D + lane * 4] = o;
}

// ---------------------------------------------------------------------------
// 3. FUSED dual-B GEMM + node loss:
//    blockIdx.y<4: attention colsum path + elu(W1) path (MFMA-bound)
//    blockIdx.y>=4: node loss on emb[z] (gather/shfl latency-bound)
// ---------------------------------------------------------------------------
__global__ void __launch_bounds__(256)
gemm_dual_nl(const __hip_bfloat16* __restrict__ embBase,
             const __hip_bfloat16* __restrict__ conv,
             __hip_bfloat16* __restrict__ xbuf,
             float* __restrict__ spacc,
             const int* __restrict__ nbr_idx,
             const int* __restrict__ neg_idx,
             const int* __restrict__ deg,
             float* __restrict__ nlpart) {
    __shared__ __align__(16) __hip_bfloat16 As[64 * LDP];
    __shared__ __align__(16) __hip_bfloat16 Bsa[64 * LDP];
    __shared__ __align__(16) __hip_bfloat16 Bsw[64 * LDP];
    int z = blockIdx.z;
    if (blockIdx.y < 4) {
        const __hip_bfloat16* A = embBase + (size_t)z * N * D;
        const __hip_bfloat16* Ba = conv + OFF_ATTW;
        const __hip_bfloat16* Bw = conv + OFF_W1;
        int bm = blockIdx.x * 64, bn = blockIdx.y * 64;
        int tid = threadIdx.x, wave = tid >> 6, lane = tid & 63;
        int quad = lane >> 4, l15 = lane & 15;
        int wr = (wave & 1) * 32, wc = (wave >> 1) * 32;
        facc4 accA[2][2] = {};
        facc4 accW[2][2] = {};
        int sr = tid >> 2, kq = (tid & 3) * 8;
        for (int k0 = 0; k0 < D; k0 += 32) {
            *(bfrag8*)&As[sr * LDP + kq]  = *(const bfrag8*)&A[(size_t)(bm + sr) * D + k0 + kq];
            *(bfrag8*)&Bsa[sr * LDP + kq] = *(const bfrag8*)&Ba[(size_t)(bn + sr) * D + k0 + kq];
            *(bfrag8*)&Bsw[sr * LDP + kq] = *(const bfrag8*)&Bw[(size_t)(bn + sr) * D + k0 + kq];
            __syncthreads();
            bfrag8 af[2], ba[2], bw[2];
            #pragma unroll
            for (int mi = 0; mi < 2; mi++)
                af[mi] = *(const bfrag8*)&As[(wr + mi * 16 + l15) * LDP + quad * 8];
            #pragma unroll
            for (int ni = 0; ni < 2; ni++) {
                ba[ni] = *(const bfrag8*)&Bsa[(wc + ni * 16 + l15) * LDP + quad * 8];
                bw[ni] = *(const bfrag8*)&Bsw[(wc + ni * 16 + l15) * LDP + quad * 8];
            }
            #pragma unroll
            for (int mi = 0; mi < 2; mi++)
                #pragma unroll
                for (int ni = 0; ni < 2; ni++) {
                    accA[mi][ni] = mfma16(af[mi], ba[ni], accA[mi][ni]);
                    accW[mi][ni] = mfma16(af[mi], bw[ni], accW[mi][ni]);
                }
            __syncthreads();
        }
        float cs[2] = {0.f, 0.f};
        #pragma unroll
        for (int mi = 0; mi < 2; mi++) {
            #pragma unroll
            for (int ni = 0; ni < 2; ni++) {
                int col = bn + wc + ni * 16 + l15;
                float battb = b2f(conv[OFF_ATTB + col]);
                float bb1   = b2f(conv[OFF_B1 + col]);
                #pragma unroll
                for (int r = 0; r < 4; r++) {
                    int row = bm + wr + mi * 16 + quad * 4 + r;
                    cs[ni] += tanhf(accA[mi][ni][r] + battb);
                    float v = accW[mi][ni][r] + bb1;
                    v = v > 0.f ? v : expm1f(v);
                    xbuf[(size_t)z * N * D + (size_t)row * D + col] = __float2bfloat16(v);
                }
            }
        }
        #pragma unroll
        for (int ni = 0; ni < 2; ni++) {
            float v = cs[ni];
            v += __shfl_xor(v, 16); v += __shfl_xor(v, 32);
            if (quad == 0) {
                int col = bn + wc + ni * 16 + l15;
                atomicAdd(&spacc[(size_t)z * D + col], v);
            }
        }
    } else {
        // ---- node loss for 4 nodes (one per wave)
        int wave = threadIdx.x >> 6, lane = threadIdx.x & 63;
        int nb = blockIdx.x * 16 + (blockIdx.y - 4);   // [0,1024)
        int n = nb * 4 + wave;
        const __hip_bfloat16* emb = embBase + (size_t)z * N * D;
        int dg = deg[z * N + n];
        int ipv = 0, igv = 0;
        if (lane < MAXDEG) {
            ipv = nbr_idx[((size_t)z * N + n) * MAXDEG + lane];
            igv = neg_idx[((size_t)z * N + n) * MAXDEG + lane];
        }
        ushort4 ar = *(const ushort4*)&emb[(size_t)n * D + lane * 4];
        float a[4] = {bfbits2f(ar.x), bfbits2f(ar.y), bfbits2f(ar.z), bfbits2f(ar.w)};
        float s = 0.f;
        int k = 0;
        for (; k + 1 < dg; k += 2) {
            int jp0 = __shfl(ipv, k), jn0 = __shfl(igv, k);
            int jp1 = __shfl(ipv, k + 1), jn1 = __shfl(igv, k + 1);
            ushort4 pr0 = *(const ushort4*)&emb[(size_t)jp0 * D + lane * 4];
            ushort4 nr0 = *(const ushort4*)&emb[(size_t)jn0 * D + lane * 4];
            ushort4 pr1 = *(const ushort4*)&emb[(size_t)jp1 * D + lane * 4];
            ushort4 nr1 = *(const ushort4*)&emb[(size_t)jn1 * D + lane * 4];
            float dp0, dn0, dp1, dn1;
            {
                float x0 = a[0] - bfbits2f(pr0.x) + EPS_PD, y0 = a[0] - bfbits2f(nr0.x) + EPS_PD;
                float x1 = a[1] - bfbits2f(pr0.y) + EPS_PD, y1 = a[1] - bfbits2f(nr0.y) + EPS_PD;
                float x2 = a[2] - bfbits2f(pr0.z) + EPS_PD, y2 = a[2] - bfbits2f(nr0.z) + EPS_PD;
                float x3 = a[3] - bfbits2f(pr0.w) + EPS_PD, y3 = a[3] - bfbits2f(nr0.w) + EPS_PD;
                dp0 = x0 * x0 + x1 * x1 + x2 * x2 + x3 * x3;
                dn0 = y0 * y0 + y1 * y1 + y2 * y2 + y3 * y3;
            }
            {
                float x0 = a[0] - bfbits2f(pr1.x) + EPS_PD, y0 = a[0] - bfbits2f(nr1.x) + EPS_PD;
                float x1 = a[1] - bfbits2f(pr1.y) + EPS_PD, y1 = a[1] - bfbits2f(nr1.y) + EPS_PD;
                float x2 = a[2] - bfbits2f(pr1.z) + EPS_PD, y2 = a[2] - bfbits2f(nr1.z) + EPS_PD;
                float x3 = a[3] - bfbits2f(pr1.w) + EPS_PD, y3 = a[3] - bfbits2f(nr1.w) + EPS_PD;
                dp1 = x0 * x0 + x1 * x1 + x2 * x2 + x3 * x3;
                dn1 = y0 * y0 + y1 * y1 + y2 * y2 + y3 * y3;
            }
            #pragma unroll
            for (int st = 1; st <= 32; st <<= 1) {
                dp0 += __shfl_xor(dp0, st); dn0 += __shfl_xor(dn0, st);
                dp1 += __shfl_xor(dp1, st); dn1 += __shfl_xor(dn1, st);
            }
            float v0 = dp0 - dn0 + MARGIN; s += v0 > 0.f ? v0 : 0.f;
            float v1 = dp1 - dn1 + MARGIN; s += v1 > 0.f ? v1 : 0.f;
        }
        if (k < dg) {
            int jp = __shfl(ipv, k), jn = __shfl(igv, k);
            ushort4 pr = *(const ushort4*)&emb[(size_t)jp * D + lane * 4];
            ushort4 nr = *(const ushort4*)&emb[(size_t)jn * D + lane * 4];
            float x0 = a[0] - bfbits2f(pr.x) + EPS_PD, y0 = a[0] - bfbits2f(nr.x) + EPS_PD;
            float x1 = a[1] - bfbits2f(pr.y) + EPS_PD, y1 = a[1] - bfbits2f(nr.y) + EPS_PD;
            float x2 = a[2] - bfbits2f(pr.z) + EPS_PD, y2 = a[2] - bfbits2f(nr.z) + EPS_PD;
            float x3 = a[3] - bfbits2f(pr.w) + EPS_PD, y3 = a[3] - bfbits2f(nr.w) + EPS_PD;
            float dp = x0 * x0 + x1 * x1 + x2 * x2 + x3 * x3;
            float dn = y0 * y0 + y1 * y1 + y2 * y2 + y3 * y3;
            #pragma unroll
            for (int st = 1; st <= 32; st <<= 1) { dp += __shfl_xor(dp, st); dn += __shfl_xor(dn, st); }
            float v = dp - dn + MARGIN;
            s += v > 0.f ? v : 0.f;
        }
        if (lane == 0) nlpart[z * N + n] = s / (float)dg;
    }
}

// ---------------------------------------------------------------------------
// 4. proj2 GEMM with fused row-normalize: block = 16 rows × all 256 cols.
// ---------------------------------------------------------------------------
__global__ void __launch_bounds__(256)
gemm_w2_norm(const __hip_bfloat16* __restrict__ xbase,
             const __hip_bfloat16* __restrict__ conv,
             __hip_bfloat16* __restrict__ qbase) {
    int z = blockIdx.z;
    const __hip_bfloat16* A = xbase + (size_t)z * N * D;
    const __hip_bfloat16* B = conv + OFF_W2;
    __shared__ __align__(16) __hip_bfloat16 As[16 * LDP];
    __shared__ __align__(16) __hip_bfloat16 Bs[256 * LDP];
    __shared__ float sred[4][16];
    int bm = blockIdx.x * 16;
    int tid = threadIdx.x, wave = tid >> 6, lane = tid & 63;
    int quad = lane >> 4, l15 = lane & 15;
    int wc = wave * 64;
    facc4 acc[4] = {};
    for (int k0 = 0; k0 < D; k0 += 32) {
        if (tid < 64) {
            int r = tid >> 2, kq = (tid & 3) * 8;
            *(bfrag8*)&As[r * LDP + kq] = *(const bfrag8*)&A[(size_t)(bm + r) * D + k0 + kq];
        }
        #pragma unroll
        for (int i = 0; i < 4; i++) {
            int f = tid + 256 * i;          // 1024 fragments of B
            int r = f >> 2, kq = (f & 3) * 8;
            *(bfrag8*)&Bs[r * LDP + kq] = *(const bfrag8*)&B[(size_t)r * D + k0 + kq];
        }
        __syncthreads();
        bfrag8 af = *(const bfrag8*)&As[l15 * LDP + quad * 8];
        #pragma unroll
        for (int ni = 0; ni < 4; ni++) {
            bfrag8 bf = *(const bfrag8*)&Bs[(wc + ni * 16 + l15) * LDP + quad * 8];
            acc[ni] = mfma16(af, bf, acc[ni]);
        }
        __syncthreads();
    }
    float vv[4][4];   // [ni][r], bias applied
    #pragma unroll
    for (int ni = 0; ni < 4; ni++) {
        float bb = b2f(conv[OFF_B2 + wc + ni * 16 + l15]);
        #pragma unroll
        for (int r = 0; r < 4; r++) vv[ni][r] = acc[ni][r] + bb;
    }
    #pragma unroll
    for (int r = 0; r < 4; r++) {
        float ss = vv[0][r] * vv[0][r] + vv[1][r] * vv[1][r] +
                   vv[2][r] * vv[2][r] + vv[3][r] * vv[3][r];
        ss += __shfl_xor(ss, 1); ss += __shfl_xor(ss, 2);
        ss += __shfl_xor(ss, 4); ss += __shfl_xor(ss, 8);
        if (l15 == 0) sred[wave][quad * 4 + r] = ss;
    }
    __syncthreads();
    #pragma unroll
    for (int r = 0; r < 4; r++) {
        int rl = quad * 4 + r;
        float ssum = sred[0][rl] + sred[1][rl] + sred[2][rl] + sred[3][rl];
        float inv = rsqrtf(ssum + 1e-30f);
        int row = bm + rl;
        #pragma unroll
        for (int ni = 0; ni < 4; ni++)
            qbase[(size_t)z * N * D + (size_t)row * D + wc + ni * 16 + l15] =
                __float2bfloat16(vv[ni][r] * inv);
    }
}

// ---------------------------------------------------------------------------
// 5. FUSED sim + posdot + z_mp:
//    blockIdx.y<32:  sim MFMA 128x128 tile, BK=128 (2 K-steps, half barriers)
//    32<=y<64:       posdot for pair (gather, latency-bound)
//    y==64:          beta reduce (redundant per block) + z_mp output slice
// ---------------------------------------------------------------------------
__global__ void __launch_bounds__(256)
sim_pd_zmp(const __hip_bfloat16* __restrict__ q,
           float* __restrict__ rowsum, float* __restrict__ colsum,
           const __hip_bfloat16* __restrict__ embBase,
           const int* __restrict__ nbr_idx, const float* __restrict__ nbr_val,
           const int* __restrict__ deg,
           float* __restrict__ pdrow, float* __restrict__ pdcol,
           const float* __restrict__ spacc,
           const __hip_bfloat16* __restrict__ conv,
           const int* __restrict__ counter,
           void* __restrict__ out) {
    __shared__ __align__(16) __hip_bfloat16 As[128 * 128];
    __shared__ __align__(16) __hip_bfloat16 Bs[128 * 128];
    int pair = blockIdx.z;
    int y = blockIdx.y;
    if (y < 32) {
        const __hip_bfloat16* Qa = q + (size_t)pair * N * D;
        const __hip_bfloat16* Qb = q + (size_t)2 * N * D;
        int bm = blockIdx.x * 128, bn = y * 128;
        int tid = threadIdx.x, wave = tid >> 6, lane = tid & 63;
        int quad = lane >> 4, l15 = lane & 15;
        int wr = (wave & 1) * 64, wc = (wave >> 1) * 64;
        facc4 acc[4][4] = {};
        int sr0 = tid >> 4;                 // 0..15 (row base)
        int cc  = tid & 15;                 // lds chunk slot (16 chunks/row)
        for (int k0 = 0; k0 < D; k0 += 128) {
            #pragma unroll
            for (int i = 0; i < 8; i++) {
                int r = sr0 + 16 * i;
                int cg = (cc ^ (r & 7)) * 8;          // swizzled global chunk
                gl_lds16(&Qa[(size_t)(bm + r) * D + k0 + cg], &As[r * 128 + cc * 8]);
                gl_lds16(&Qb[(size_t)(bn + r) * D + k0 + cg], &Bs[r * 128 + cc * 8]);
            }
            __syncthreads();
            #pragma unroll
            for (int kk = 0; kk < 128; kk += 32) {
                int kb = kk >> 3;
                bfrag8 af[4], bfr[4];
                #pragma unroll
                for (int mi = 0; mi < 4; mi++) {
                    int R = wr + mi * 16 + l15;
                    int pc = ((kb + quad) ^ (l15 & 7)) * 8;
                    af[mi] = *(const bfrag8*)&As[R * 128 + pc];
                }
                #pragma unroll
                for (int ni = 0; ni < 4; ni++) {
                    int R = wc + ni * 16 + l15;
                    int pc = ((kb + quad) ^ (l15 & 7)) * 8;
                    bfr[ni] = *(const bfrag8*)&Bs[R * 128 + pc];
                }
                #pragma unroll
                for (int mi = 0; mi < 4; mi++)
                    #pragma unroll
                    for (int ni = 0; ni < 4; ni++)
                        acc[mi][ni] = mfma16(af[mi], bfr[ni], acc[mi][ni]);
            }
            __syncthreads();
        }
        constexpr float invtau = 1.0f / TAU;
        float rs[4][4];
        float cs[4] = {0.f, 0.f, 0.f, 0.f};
        #pragma unroll
        for (int mi = 0; mi < 4; mi++)
            #pragma unroll
            for (int r = 0; r < 4; r++) rs[mi][r] = 0.f;
        #pragma unroll
        for (int mi = 0; mi < 4; mi++)
            #pragma unroll
            for (int ni = 0; ni < 4; ni++)
                #pragma unroll
                for (int r = 0; r < 4; r++) {
                    float e = __expf(acc[mi][ni][r] * invtau);
                    rs[mi][r] += e;
                    cs[ni] += e;
                }
        #pragma unroll
        for (int mi = 0; mi < 4; mi++)
            #pragma unroll
            for (int r = 0; r < 4; r++) {
                float v = rs[mi][r];
                v += __shfl_xor(v, 1); v += __shfl_xor(v, 2);
                v += __shfl_xor(v, 4); v += __shfl_xor(v, 8);
                rs[mi][r] = v;
            }
        if (l15 == 0) {
            #pragma unroll
            for (int mi = 0; mi < 4; mi++)
                #pragma unroll
                for (int r = 0; r < 4; r++)
                    atomicAdd(&rowsum[(size_t)pair * N + bm + wr + mi * 16 + quad * 4 + r], rs[mi][r]);
        }
        #pragma unroll
        for (int ni = 0; ni < 4; ni++) {
            float v = cs[ni];
            v += __shfl_xor(v, 16); v += __shfl_xor(v, 32);
            if (quad == 0)
                atomicAdd(&colsum[(size_t)pair * N + bn + wc + ni * 16 + l15], v);
        }
    } else if (y < 64) {
        // ---- posdot for 4 nodes (one per wave)
        int wave = threadIdx.x >> 6, lane = threadIdx.x & 63;
        int nb = blockIdx.x * 32 + (y - 32);    // [0,1024)
        int n = nb * 4 + wave;
        const __hip_bfloat16* Qa = q + (size_t)pair * N * D;
        const __hip_bfloat16* Qb = q + (size_t)2 * N * D;
        int dg = deg[pair * N + n];
        int idxv = 0; float valv = 0.f;
        if (lane < MAXDEG) {
            idxv = nbr_idx[((size_t)pair * N + n) * MAXDEG + lane];
            valv = nbr_val[((size_t)pair * N + n) * MAXDEG + lane];
        }
        const float invtau = 1.0f / TAU;
        ushort4 ar = *(const ushort4*)&Qa[(size_t)n * D + lane * 4];
        ushort4 br = *(const ushort4*)&Qb[(size_t)n * D + lane * 4];
        float a[4] = {bfbits2f(ar.x), bfbits2f(ar.y), bfbits2f(ar.z), bfbits2f(ar.w)};
        float b[4] = {bfbits2f(br.x), bfbits2f(br.y), bfbits2f(br.z), bfbits2f(br.w)};
        float sr = 0.f, sc = 0.f;
        int k = 0;
        for (; k + 1 < dg; k += 2) {
            int j0 = __shfl(idxv, k), j1 = __shfl(idxv, k + 1);
            float vk0 = __shfl(valv, k), vk1 = __shfl(valv, k + 1);
            ushort4 pj0 = *(const ushort4*)&Qb[(size_t)j0 * D + lane * 4];
            ushort4 aj0 = *(const ushort4*)&Qa[(size_t)j0 * D + lane * 4];
            ushort4 pj1 = *(const ushort4*)&Qb[(size_t)j1 * D + lane * 4];
            ushort4 aj1 = *(const ushort4*)&Qa[(size_t)j1 * D + lane * 4];
            float dr0 = a[0] * bfbits2f(pj0.x) + a[1] * bfbits2f(pj0.y) +
                        a[2] * bfbits2f(pj0.z) + a[3] * bfbits2f(pj0.w);
            float dc0 = b[0] * bfbits2f(aj0.x) + b[1] * bfbits2f(aj0.y) +
                        b[2] * bfbits2f(aj0.z) + b[3] * bfbits2f(aj0.w);
            float dr1 = a[0] * bfbits2f(pj1.x) + a[1] * bfbits2f(pj1.y) +
                        a[2] * bfbits2f(pj1.z) + a[3] * bfbits2f(pj1.w);
            float dc1 = b[0] * bfbits2f(aj1.x) + b[1] * bfbits2f(aj1.y) +
                        b[2] * bfbits2f(aj1.z) + b[3] * bfbits2f(aj1.w);
            #pragma unroll
            for (int s2 = 1; s2 <= 32; s2 <<= 1) {
                dr0 += __shfl_xor(dr0, s2); dc0 += __shfl_xor(dc0, s2);
                dr1 += __shfl_xor(dr1, s2); dc1 += __shfl_xor(dc1, s2);
            }
            sr += __expf(dr0 * invtau) * vk0 + __expf(dr1 * invtau) * vk1;
            sc += __expf(dc0 * invtau) * vk0 + __expf(dc1 * invtau) * vk1;
        }
        if (k < dg) {
            int j = __shfl(idxv, k);
            float vk = __shfl(valv, k);
            ushort4 pj = *(const ushort4*)&Qb[(size_t)j * D + lane * 4];
            ushort4 aj = *(const ushort4*)&Qa[(size_t)j * D + lane * 4];
            float dr = a[0] * bfbits2f(pj.x) + a[1] * bfbits2f(pj.y) +
                       a[2] * bfbits2f(pj.z) + a[3] * bfbits2f(pj.w);
            float dc = b[0] * bfbits2f(aj.x) + b[1] * bfbits2f(aj.y) +
                       b[2] * bfbits2f(aj.z) + b[3] * bfbits2f(aj.w);
            #pragma unroll
            for (int s2 = 1; s2 <= 32; s2 <<= 1) { dr += __shfl_xor(dr, s2); dc += __shfl_xor(dc, s2); }
            sr += __expf(dr * invtau) * vk;
            sc += __expf(dc * invtau) * vk;
        }
        if (lane == 0) { pdrow[pair * N + n] = sr; pdcol[pair * N + n] = sc; }
    } else {
        // ---- beta (redundant reduce per block) + z_mp output slice
        int bf = get_bf(counter);
        int t = threadIdx.x;
        float* red = (float*)As;     // alias LDS
        float* w   = (float*)Bs;
        for (int p = 0; p < P; p++) {
            float v = (spacc[p * D + t] / (float)N) * b2f(conv[OFF_AV + t]);
            red[t] = v;
            __syncthreads();
            for (int s = 128; s > 0; s >>= 1) { if (t < s) red[t] += red[t + s]; __syncthreads(); }
            if (t == 0) w[p] = red[0];
            __syncthreads();
        }
        float m = fmaxf(w[0], fmaxf(w[1], w[2]));
        float e0 = __expf(w[0] - m), e1 = __expf(w[1] - m), e2 = __expf(w[2] - m);
        float ssum = e0 + e1 + e2;
        float b0 = e0 / ssum, b1 = e1 / ssum, b2 = e2 / ssum;
        int slice = pair * 32 + blockIdx.x;       // [0,64)
        int base = slice * (N * D / 64);
        for (int e = t * 4; e < N * D / 64; e += 256 * 4) {
            int i = base + e;
            ushort4 x0 = *(const ushort4*)&embBase[i];
            ushort4 x1 = *(const ushort4*)&embBase[(size_t)N * D + i];
            ushort4 x2 = *(const ushort4*)&embBase[(size_t)2 * N * D + i];
            float v[4];
            v[0] = b0 * bfbits2f(x0.x) + b1 * bfbits2f(x1.x) + b2 * bfbits2f(x2.x);
            v[1] = b0 * bfbits2f(x0.y) + b1 * bfbits2f(x1.y) + b2 * bfbits2f(x2.y);
            v[2] = b0 * bfbits2f(x0.z) + b1 * bfbits2f(x1.z) + b2 * bfbits2f(x2.z);
            v[3] = b0 * bfbits2f(x0.w) + b1 * bfbits2f(x1.w) + b2 * bfbits2f(x2.w);
            if (bf) {
                ushort4 ov;
                ov.x = f2bfbits(v[0]); ov.y = f2bfbits(v[1]);
                ov.z = f2bfbits(v[2]); ov.w = f2bfbits(v[3]);
                *(ushort4*)&((__hip_bfloat16*)out)[i] = ov;
            } else {
                float* o = (float*)out;
                o[i] = v[0]; o[i + 1] = v[1]; o[i + 2] = v[2]; o[i + 3] = v[3];
            }
        }
    }
}

// ---------------------------------------------------------------------------
// 6. finalize: single block -> loss reduce + write out[N*D].
// ---------------------------------------------------------------------------
__global__ void __launch_bounds__(256)
finalize_loss(const float* __restrict__ nlpart,
              const float* __restrict__ rowsum, const float* __restrict__ colsum,
              const float* __restrict__ pdrow, const float* __restrict__ pdcol,
              const int* __restrict__ counter,
              void* __restrict__ out) {
    int bf = get_bf(counter);
    int t = threadIdx.x;
    __shared__ float red[256];
    float s = 0.f;
    for (int i = t; i < P * N; i += 256) s += nlpart[i];
    for (int i = t; i < 2 * N; i += 256) {
        float l12 = -logf(pdrow[i] / (rowsum[i] + 1e-8f));
        float l21 = -logf(pdcol[i] / (colsum[i] + 1e-8f));
        s += (0.5f * l12 + 0.5f * l21) / (float)N;
    }
    red[t] = s;
    __syncthreads();
    for (int st = 128; st > 0; st >>= 1) { if (t < st) red[t] += red[t + st]; __syncthreads(); }
    if (t == 0) {
        if (bf) ((__hip_bfloat16*)out)[(size_t)N * D] = __float2bfloat16(red[0]);
        else    ((float*)out)[(size_t)N * D] = red[0];
    }
}

extern "C" void kernel_launch(void* const* d_in, const int* in_sizes, int n_in,
                              void* d_out, int out_size, void* d_ws, size_t ws_size,
                              hipStream_t stream) {
    const void* h        = d_in[0];
    const void* mps      = d_in[1];
    const void* W_gcn    = d_in[2];
    const void* b_gcn    = d_in[3];
    const void* prelu_a  = d_in[4];
    const void* att_fc_W = d_in[5];
    const void* att_fc_b = d_in[6];
    const void* att_vec  = d_in[7];
    const void* proj_W1  = d_in[8];
    const void* proj_b1  = d_in[9];
    const void* proj_W2  = d_in[10];
    const void* proj_b2  = d_in[11];

    char* ws = (char*)d_ws;
    size_t off = 0;
    auto alloc = [&](size_t bytes) -> char* {
        char* p = ws + off;
        off = (off + bytes + 255) & ~(size_t)255;
        return p;
    };
    __hip_bfloat16* conv = (__hip_bfloat16*)alloc((size_t)CONV_TOTAL * 2);
    __hip_bfloat16* xbuf = (__hip_bfloat16*)alloc((size_t)P * N * D * 2);
    __hip_bfloat16* emb  = (__hip_bfloat16*)alloc((size_t)P * N * D * 2);
    __hip_bfloat16* q    = (__hip_bfloat16*)alloc((size_t)P * N * D * 2);
    int*   nbr_idx = (int*)alloc((size_t)P * N * MAXDEG * 4);
    float* nbr_val = (float*)alloc((size_t)P * N * MAXDEG * 4);
    int*   neg_idx = (int*)alloc((size_t)P * N * MAXDEG * 4);
    int*   deg     = (int*)alloc((size_t)P * N * 4);
    float* nlpart  = (float*)alloc((size_t)P * N * 4);
    float* pdrow   = (float*)alloc((size_t)2 * N * 4);
    float* pdcol   = (float*)alloc((size_t)2 * N * 4);
    char* zero_begin = ws + off;
    float* rowsum = (float*)alloc((size_t)2 * N * 4);
    float* colsum = (float*)alloc((size_t)2 * N * 4);
    float* spacc  = (float*)alloc((size_t)P * D * 4);
    size_t zero_bytes = (size_t)((ws + off) - zero_begin);
    int*   counter = (int*)alloc(16);   // NOT zeroed: detect uses atomicMax sentinel

    // 0. dtype detection + zero the atomic-accumulator region (one dispatch)
    detect_dtype<<<1024, 256, 0, stream>>>((const unsigned int*)mps, 2 * 1024 * 1024,
                                           counter, (float*)zero_begin,
                                           (int)(zero_bytes / 4));

    // 1. fused: triple GEMM (raw h/Wg) + sparse extraction + small-weight convert
    stage2<<<256 + P * N + 64, 256, 0, stream>>>(h, W_gcn, mps,
                                                 att_fc_W, proj_W1, proj_W2, b_gcn,
                                                 att_fc_b, att_vec, prelu_a, proj_b1, proj_b2,
                                                 counter, conv, xbuf,
                                                 nbr_idx, nbr_val, neg_idx, deg);

    // 2. emb[z] = prelu(spmm + bias)
    spmm_prelu<<<dim3(N / 4, 1, P), 256, 0, stream>>>(xbuf, nbr_idx, nbr_val, deg, conv, emb);

    // 3. fused: spacc/elu GEMM + node loss
    gemm_dual_nl<<<dim3(64, 20, P), 256, 0, stream>>>(emb, conv, xbuf, spacc,
                                                      nbr_idx, neg_idx, deg, nlpart);

    // 4. q[z] = rownorm(xbuf[z] @ W2^T + b2), fused
    gemm_w2_norm<<<dim3(N / 16, 1, P), 256, 0, stream>>>(xbuf, conv, q);

    // 5. fused: sim (BK=128) rowsum/colsum + posdot + beta/z_mp output
    sim_pd_zmp<<<dim3(32, 65, 2), 256, 0, stream>>>(q, rowsum, colsum, emb,
                                                    nbr_idx, nbr_val, deg,
                                                    pdrow, pdcol, spacc, conv,
                                                    counter, d_out);

    // 6. finalize: loss scalar
    finalize_loss<<<1, 256, 0, stream>>>(nlpart, rowsum, colsum, pdrow, pdcol,
                                         counter, d_out);
}

// Round 7
// 473.143 us; speedup vs baseline: 1.0014x; 1.0014x over previous
//
#include <hip/hip_runtime.h>
#include <hip/hip_bf16.h>

// Problem constants (Mp_encoder): N nodes, D dims, P metapaths.
constexpr int N = 4096;
constexpr int D = 256;
constexpr int P = 3;
constexpr int MAXDEG = 17;       // K+1
constexpr float TAU = 0.8f;
constexpr float MARGIN = 0.1f;
constexpr float EPS_PD = 1e-6f;

constexpr int LDP = 40;          // LDS k-stride for 64-tiles (2-way max conflicts)

// bf16 conversion-area offsets (elements), all 256-aligned
constexpr int OFF_ATTW = 1245184;       // 65536
constexpr int OFF_W1   = 1310720;       // 65536
constexpr int OFF_W2   = 1376256;       // 65536
constexpr int OFF_BG   = 1441792;       // 768
constexpr int OFF_ATTB = 1442560;       // 256
constexpr int OFF_AV   = 1442816;       // 256
constexpr int OFF_PA   = 1443072;       // 3 (reserve 256)
constexpr int OFF_B1   = 1443328;       // 256
constexpr int OFF_B2   = 1443584;       // 256
constexpr int CONV_TOTAL = 1443840;

typedef __attribute__((ext_vector_type(8))) short bfrag8;
typedef __attribute__((ext_vector_type(4))) float facc4;

__device__ inline facc4 mfma16(bfrag8 a, bfrag8 b, facc4 c) {
    return __builtin_amdgcn_mfma_f32_16x16x32_bf16(a, b, c, 0, 0, 0);
}
__device__ inline float b2f(__hip_bfloat16 v) { return __bfloat162float(v); }
__device__ inline float bfbits2f(unsigned short u) {
    return __uint_as_float(((unsigned int)u) << 16);
}
__device__ inline unsigned short f2bfbits(float v) {
    __hip_bfloat16 t = __float2bfloat16(v);
    return *(unsigned short*)&t;
}
__device__ inline int get_bf(const int* __restrict__ counter) { return counter[0] > 100; }

__device__ inline float load_in(const void* p, size_t i, int bf) {
    return bf ? __bfloat162float(((const __hip_bfloat16*)p)[i])
              : ((const float*)p)[i];
}

// async global->LDS, 16 bytes per lane; dest = wave-uniform base + lane*16
__device__ __forceinline__ void gl_lds16(const __hip_bfloat16* g, __hip_bfloat16* l) {
    __builtin_amdgcn_global_load_lds(
        (const __attribute__((address_space(1))) unsigned int*)g,
        (__attribute__((address_space(3))) unsigned int*)l, 16, 0, 0);
}

// ---------------------------------------------------------------------------
// 0. dtype detection (atomicMax sentinel) + zero atomic-accumulator region.
// ---------------------------------------------------------------------------
__global__ void __launch_bounds__(256)
detect_dtype(const unsigned int* __restrict__ w, int nwords,
             int* __restrict__ counter,
             float* __restrict__ zbuf, int nz) {
    int t0 = blockIdx.x * blockDim.x + threadIdx.x;
    if (t0 < nz) zbuf[t0] = 0.f;
    int stride = gridDim.x * blockDim.x;
    int c = 0;
    for (int i = t0; i < nwords; i += stride) {
        unsigned int x = w[i];
        if ((x & 0xFFFF0000u) == 0u && x != 0u) c++;
    }
    for (int s = 32; s > 0; s >>= 1) c += __shfl_down(c, s);
    if ((threadIdx.x & 63) == 0 && c > 0) atomicMax(counter, 1 << 20);
}

// ---------------------------------------------------------------------------
// 1. FUSED stage2: one dispatch =
//    blocks [0,256):          triple-B GCN GEMM reading RAW h / W_gcn
//    blocks [256,256+P*N):    sparse extraction (per (p,n) row of mps)
//    blocks [256+P*N, +64):   convert small dense weights to bf16 staging
// ---------------------------------------------------------------------------
__global__ void __launch_bounds__(256)
stage2(const void* __restrict__ h, const void* __restrict__ wg,
       const void* __restrict__ mps,
       const void* attw, const void* w1, const void* w2,
       const void* bg, const void* attb, const void* av,
       const void* pa, const void* b1, const void* b2,
       const int* __restrict__ counter,
       __hip_bfloat16* __restrict__ conv,
       __hip_bfloat16* __restrict__ xbuf,
       int* __restrict__ nbr_idx, float* __restrict__ nbr_val,
       int* __restrict__ neg_idx, int* __restrict__ deg) {
    __shared__ __align__(16) __hip_bfloat16 As[64 * LDP];
    __shared__ __align__(16) __hip_bfloat16 Bs[3][64 * LDP];
    int bid = blockIdx.x;
    int bf = get_bf(counter);
    if (bid < 256) {
        // ---- triple GEMM: X[z] = h @ Wg[z]^T, raw-input in-register convert
        int bm = (bid & 63) * 64, bn = (bid >> 6) * 64;
        int tid = threadIdx.x, wave = tid >> 6, lane = tid & 63;
        int quad = lane >> 4, l15 = lane & 15;
        int wr = (wave & 1) * 32, wc = (wave >> 1) * 32;
        facc4 acc[3][2][2] = {};
        int sr = tid >> 2, kq = (tid & 3) * 8;
        for (int k0 = 0; k0 < D; k0 += 32) {
            if (bf) {
                *(bfrag8*)&As[sr * LDP + kq] =
                    *(const bfrag8*)((const unsigned short*)h + (size_t)(bm + sr) * D + k0 + kq);
                #pragma unroll
                for (int z = 0; z < 3; z++)
                    *(bfrag8*)&Bs[z][sr * LDP + kq] =
                        *(const bfrag8*)((const unsigned short*)wg +
                                         (size_t)z * D * D + (size_t)(bn + sr) * D + k0 + kq);
            } else {
                const float* hp = (const float*)h + (size_t)(bm + sr) * D + k0 + kq;
                float4 a0 = *(const float4*)hp, a1 = *(const float4*)(hp + 4);
                bfrag8 t;
                t[0] = f2bfbits(a0.x); t[1] = f2bfbits(a0.y);
                t[2] = f2bfbits(a0.z); t[3] = f2bfbits(a0.w);
                t[4] = f2bfbits(a1.x); t[5] = f2bfbits(a1.y);
                t[6] = f2bfbits(a1.z); t[7] = f2bfbits(a1.w);
                *(bfrag8*)&As[sr * LDP + kq] = t;
                #pragma unroll
                for (int z = 0; z < 3; z++) {
                    const float* wp = (const float*)wg +
                        (size_t)z * D * D + (size_t)(bn + sr) * D + k0 + kq;
                    float4 b0 = *(const float4*)wp, b1v = *(const float4*)(wp + 4);
                    bfrag8 u;
                    u[0] = f2bfbits(b0.x);  u[1] = f2bfbits(b0.y);
                    u[2] = f2bfbits(b0.z);  u[3] = f2bfbits(b0.w);
                    u[4] = f2bfbits(b1v.x); u[5] = f2bfbits(b1v.y);
                    u[6] = f2bfbits(b1v.z); u[7] = f2bfbits(b1v.w);
                    *(bfrag8*)&Bs[z][sr * LDP + kq] = u;
                }
            }
            __syncthreads();
            bfrag8 af[2];
            #pragma unroll
            for (int mi = 0; mi < 2; mi++)
                af[mi] = *(const bfrag8*)&As[(wr + mi * 16 + l15) * LDP + quad * 8];
            __builtin_amdgcn_s_setprio(1);
            #pragma unroll
            for (int z = 0; z < 3; z++) {
                bfrag8 bfr[2];
                #pragma unroll
                for (int ni = 0; ni < 2; ni++)
                    bfr[ni] = *(const bfrag8*)&Bs[z][(wc + ni * 16 + l15) * LDP + quad * 8];
                #pragma unroll
                for (int mi = 0; mi < 2; mi++)
                    #pragma unroll
                    for (int ni = 0; ni < 2; ni++)
                        acc[z][mi][ni] = mfma16(af[mi], bfr[ni], acc[z][mi][ni]);
            }
            __builtin_amdgcn_s_setprio(0);
            __syncthreads();
        }
        #pragma unroll
        for (int z = 0; z < 3; z++)
            #pragma unroll
            for (int mi = 0; mi < 2; mi++)
                #pragma unroll
                for (int ni = 0; ni < 2; ni++) {
                    int col = bn + wc + ni * 16 + l15;
                    #pragma unroll
                    for (int r = 0; r < 4; r++) {
                        int row = bm + wr + mi * 16 + quad * 4 + r;
                        xbuf[(size_t)z * N * D + (size_t)row * D + col] =
                            __float2bfloat16(acc[z][mi][ni][r]);
                    }
                }
    } else if (bid < 256 + P * N) {
        // ---- sparse extraction for row (p,n); LDS aliased onto As
        int row = bid - 256;
        int t = threadIdx.x;
        int* cnt = (int*)As;
        int* sidx = ((int*)As) + 1;
        float* sval = (float*)(((int*)As) + 33);
        if (t == 0) *cnt = 0;
        __syncthreads();
        int e0 = t * 16;
        if (bf) {
            const uint4* base = (const uint4*)((const __hip_bfloat16*)mps + (size_t)row * N + e0);
            #pragma unroll
            for (int v = 0; v < 2; v++) {
                uint4 w = base[v];
                unsigned int ws[4] = {w.x, w.y, w.z, w.w};
                #pragma unroll
                for (int j = 0; j < 4; j++) {
                    unsigned short lo = (unsigned short)(ws[j] & 0xFFFFu);
                    unsigned short hi = (unsigned short)(ws[j] >> 16);
                    if (lo) { int k = atomicAdd(cnt, 1); if (k < 32) { sidx[k] = e0 + v * 8 + j * 2;     sval[k] = bfbits2f(lo); } }
                    if (hi) { int k = atomicAdd(cnt, 1); if (k < 32) { sidx[k] = e0 + v * 8 + j * 2 + 1; sval[k] = bfbits2f(hi); } }
                }
            }
        } else {
            const float4* base = (const float4*)((const float*)mps + (size_t)row * N + e0);
            #pragma unroll
            for (int v = 0; v < 4; v++) {
                float4 w = base[v];
                float ws[4] = {w.x, w.y, w.z, w.w};
                #pragma unroll
                for (int j = 0; j < 4; j++)
                    if (ws[j] > 0.f) { int k = atomicAdd(cnt, 1); if (k < 32) { sidx[k] = e0 + v * 4 + j; sval[k] = ws[j]; } }
            }
        }
        __syncthreads();
        if (t < 64) {
            int dg = *cnt; if (dg > MAXDEG) dg = MAXDEG;
            int myidx = 0; float myval = 0.f; int rank = 0;
            if (t < dg) {
                myidx = sidx[t]; myval = sval[t];
                for (int j = 0; j < dg; j++) rank += (sidx[j] < myidx) ? 1 : 0;
            }
            if (t < dg) { sidx[rank] = myidx; sval[rank] = myval; }
            if (t < MAXDEG) {
                nbr_idx[(size_t)row * MAXDEG + t] = (t < dg) ? sidx[t] : 0;
                nbr_val[(size_t)row * MAXDEG + t] = (t < dg) ? sval[t] : 0.f;
            }
            if (t == 0) deg[row] = dg;
            int c = t;
            bool cand = (c < dg + MAXDEG);
            bool isnbr = false;
            if (cand) for (int j = 0; j < dg; j++) isnbr |= (sidx[j] == c);
            bool nonnbr = cand && !isnbr;
            unsigned long long m = __ballot(nonnbr);
            int nrank = __popcll(m & ((c < 64) ? ((1ull << c) - 1ull) : ~0ull));
            if (nonnbr && nrank < MAXDEG) neg_idx[(size_t)row * MAXDEG + nrank] = c;
        }
    } else {
        // ---- convert small dense weights (h/W_gcn no longer staged)
        int cb = bid - (256 + P * N);
        const void* srcs[9] = {attw, w1, w2, bg, attb, av, pa, b1, b2};
        const int offs[9] = {OFF_ATTW, OFF_W1, OFF_W2, OFF_BG, OFF_ATTB,
                             OFF_AV, OFF_PA, OFF_B1, OFF_B2};
        const int lens[9] = {65536, 65536, 65536, 768, 256, 256, 3, 256, 256};
        int stride = 64 * 256;
        int t0 = cb * 256 + threadIdx.x;
        #pragma unroll
        for (int s = 0; s < 9; s++) {
            for (int i = t0; i < lens[s]; i += stride)
                conv[offs[s] + i] = __float2bfloat16(load_in(srcs[s], i, bf));
        }
    }
}

// ---------------------------------------------------------------------------
// 2. spmm + prelu: wave per node, idx/val in lane registers, 4-way unroll.
// ---------------------------------------------------------------------------
__global__ void __launch_bounds__(256)
spmm_prelu(const __hip_bfloat16* __restrict__ Xbase,
           const int* __restrict__ nbr_idx, const float* __restrict__ nbr_val,
           const int* __restrict__ deg, const __hip_bfloat16* __restrict__ conv,
           __hip_bfloat16* __restrict__ embBase) {
    int z = blockIdx.z;
    int wave = threadIdx.x >> 6, lane = threadIdx.x & 63;
    int n = blockIdx.x * 4 + wave;
    const __hip_bfloat16* X = Xbase + (size_t)z * N * D;
    int dg = deg[z * N + n];
    int idxv = 0; float valv = 0.f;
    if (lane < MAXDEG) {
        idxv = nbr_idx[((size_t)z * N + n) * MAXDEG + lane];
        valv = nbr_val[((size_t)z * N + n) * MAXDEG + lane];
    }
    float acc[4] = {0.f, 0.f, 0.f, 0.f};
    int k = 0;
    for (; k + 3 < dg; k += 4) {
        int j0 = __shfl(idxv, k), j1 = __shfl(idxv, k + 1);
        int j2 = __shfl(idxv, k + 2), j3 = __shfl(idxv, k + 3);
        float v0 = __shfl(valv, k), v1 = __shfl(valv, k + 1);
        float v2 = __shfl(valv, k + 2), v3 = __shfl(valv, k + 3);
        ushort4 x0 = *(const ushort4*)&X[(size_t)j0 * D + lane * 4];
        ushort4 x1 = *(const ushort4*)&X[(size_t)j1 * D + lane * 4];
        ushort4 x2 = *(const ushort4*)&X[(size_t)j2 * D + lane * 4];
        ushort4 x3 = *(const ushort4*)&X[(size_t)j3 * D + lane * 4];
        acc[0] += v0 * bfbits2f(x0.x) + v1 * bfbits2f(x1.x) + v2 * bfbits2f(x2.x) + v3 * bfbits2f(x3.x);
        acc[1] += v0 * bfbits2f(x0.y) + v1 * bfbits2f(x1.y) + v2 * bfbits2f(x2.y) + v3 * bfbits2f(x3.y);
        acc[2] += v0 * bfbits2f(x0.z) + v1 * bfbits2f(x1.z) + v2 * bfbits2f(x2.z) + v3 * bfbits2f(x3.z);
        acc[3] += v0 * bfbits2f(x0.w) + v1 * bfbits2f(x1.w) + v2 * bfbits2f(x2.w) + v3 * bfbits2f(x3.w);
    }
    for (; k < dg; k++) {
        int j0 = __shfl(idxv, k); float v0 = __shfl(valv, k);
        ushort4 x0 = *(const ushort4*)&X[(size_t)j0 * D + lane * 4];
        acc[0] += v0 * bfbits2f(x0.x); acc[1] += v0 * bfbits2f(x0.y);
        acc[2] += v0 * bfbits2f(x0.z); acc[3] += v0 * bfbits2f(x0.w);
    }
    ushort4 bb = *(const ushort4*)&conv[OFF_BG + z * D + lane * 4];
    float a = b2f(conv[OFF_PA + z]);
    ushort4 o;
    float v0 = acc[0] + bfbits2f(bb.x); o.x = f2bfbits(v0 > 0.f ? v0 : a * v0);
    float v1 = acc[1] + bfbits2f(bb.y); o.y = f2bfbits(v1 > 0.f ? v1 : a * v1);
    float v2 = acc[2] + bfbits2f(bb.z); o.z = f2bfbits(v2 > 0.f ? v2 : a * v2);
    float v3 = acc[3] + bfbits2f(bb.w); o.w = f2bfbits(v3 > 0.f ? v3 : a * v3);
    *(ushort4*)&embBase[(size_t)z * N * D + (size_t)n * D + lane * 4] = o;
}

// ---------------------------------------------------------------------------
// 3. FUSED dual-B GEMM + node loss:
//    blockIdx.y<4: attention colsum path + elu(W1) path (MFMA-bound)
//    blockIdx.y>=4: node loss on emb[z] (gather/shfl latency-bound)
// ---------------------------------------------------------------------------
__global__ void __launch_bounds__(256)
gemm_dual_nl(const __hip_bfloat16* __restrict__ embBase,
             const __hip_bfloat16* __restrict__ conv,
             __hip_bfloat16* __restrict__ xbuf,
             float* __restrict__ spacc,
             const int* __restrict__ nbr_idx,
             const int* __restrict__ neg_idx,
             const int* __restrict__ deg,
             float* __restrict__ nlpart) {
    __shared__ __align__(16) __hip_bfloat16 As[64 * LDP];
    __shared__ __align__(16) __hip_bfloat16 Bsa[64 * LDP];
    __shared__ __align__(16) __hip_bfloat16 Bsw[64 * LDP];
    int z = blockIdx.z;
    if (blockIdx.y < 4) {
        const __hip_bfloat16* A = embBase + (size_t)z * N * D;
        const __hip_bfloat16* Ba = conv + OFF_ATTW;
        const __hip_bfloat16* Bw = conv + OFF_W1;
        int bm = blockIdx.x * 64, bn = blockIdx.y * 64;
        int tid = threadIdx.x, wave = tid >> 6, lane = tid & 63;
        int quad = lane >> 4, l15 = lane & 15;
        int wr = (wave & 1) * 32, wc = (wave >> 1) * 32;
        facc4 accA[2][2] = {};
        facc4 accW[2][2] = {};
        int sr = tid >> 2, kq = (tid & 3) * 8;
        for (int k0 = 0; k0 < D; k0 += 32) {
            *(bfrag8*)&As[sr * LDP + kq]  = *(const bfrag8*)&A[(size_t)(bm + sr) * D + k0 + kq];
            *(bfrag8*)&Bsa[sr * LDP + kq] = *(const bfrag8*)&Ba[(size_t)(bn + sr) * D + k0 + kq];
            *(bfrag8*)&Bsw[sr * LDP + kq] = *(const bfrag8*)&Bw[(size_t)(bn + sr) * D + k0 + kq];
            __syncthreads();
            bfrag8 af[2], ba[2], bw[2];
            #pragma unroll
            for (int mi = 0; mi < 2; mi++)
                af[mi] = *(const bfrag8*)&As[(wr + mi * 16 + l15) * LDP + quad * 8];
            #pragma unroll
            for (int ni = 0; ni < 2; ni++) {
                ba[ni] = *(const bfrag8*)&Bsa[(wc + ni * 16 + l15) * LDP + quad * 8];
                bw[ni] = *(const bfrag8*)&Bsw[(wc + ni * 16 + l15) * LDP + quad * 8];
            }
            __builtin_amdgcn_s_setprio(1);
            #pragma unroll
            for (int mi = 0; mi < 2; mi++)
                #pragma unroll
                for (int ni = 0; ni < 2; ni++) {
                    accA[mi][ni] = mfma16(af[mi], ba[ni], accA[mi][ni]);
                    accW[mi][ni] = mfma16(af[mi], bw[ni], accW[mi][ni]);
                }
            __builtin_amdgcn_s_setprio(0);
            __syncthreads();
        }
        float cs[2] = {0.f, 0.f};
        #pragma unroll
        for (int mi = 0; mi < 2; mi++) {
            #pragma unroll
            for (int ni = 0; ni < 2; ni++) {
                int col = bn + wc + ni * 16 + l15;
                float battb = b2f(conv[OFF_ATTB + col]);
                float bb1   = b2f(conv[OFF_B1 + col]);
                #pragma unroll
                for (int r = 0; r < 4; r++) {
                    int row = bm + wr + mi * 16 + quad * 4 + r;
                    cs[ni] += tanhf(accA[mi][ni][r] + battb);
                    float v = accW[mi][ni][r] + bb1;
                    v = v > 0.f ? v : expm1f(v);
                    xbuf[(size_t)z * N * D + (size_t)row * D + col] = __float2bfloat16(v);
                }
            }
        }
        #pragma unroll
        for (int ni = 0; ni < 2; ni++) {
            float v = cs[ni];
            v += __shfl_xor(v, 16); v += __shfl_xor(v, 32);
            if (quad == 0) {
                int col = bn + wc + ni * 16 + l15;
                atomicAdd(&spacc[(size_t)z * D + col], v);
            }
        }
    } else {
        // ---- node loss for 4 nodes (one per wave)
        int wave = threadIdx.x >> 6, lane = threadIdx.x & 63;
        int nb = blockIdx.x * 16 + (blockIdx.y - 4);   // [0,1024)
        int n = nb * 4 + wave;
        const __hip_bfloat16* emb = embBase + (size_t)z * N * D;
        int dg = deg[z * N + n];
        int ipv = 0, igv = 0;
        if (lane < MAXDEG) {
            ipv = nbr_idx[((size_t)z * N + n) * MAXDEG + lane];
            igv = neg_idx[((size_t)z * N + n) * MAXDEG + lane];
        }
        ushort4 ar = *(const ushort4*)&emb[(size_t)n * D + lane * 4];
        float a[4] = {bfbits2f(ar.x), bfbits2f(ar.y), bfbits2f(ar.z), bfbits2f(ar.w)};
        float s = 0.f;
        int k = 0;
        for (; k + 1 < dg; k += 2) {
            int jp0 = __shfl(ipv, k), jn0 = __shfl(igv, k);
            int jp1 = __shfl(ipv, k + 1), jn1 = __shfl(igv, k + 1);
            ushort4 pr0 = *(const ushort4*)&emb[(size_t)jp0 * D + lane * 4];
            ushort4 nr0 = *(const ushort4*)&emb[(size_t)jn0 * D + lane * 4];
            ushort4 pr1 = *(const ushort4*)&emb[(size_t)jp1 * D + lane * 4];
            ushort4 nr1 = *(const ushort4*)&emb[(size_t)jn1 * D + lane * 4];
            float dp0, dn0, dp1, dn1;
            {
                float x0 = a[0] - bfbits2f(pr0.x) + EPS_PD, y0 = a[0] - bfbits2f(nr0.x) + EPS_PD;
                float x1 = a[1] - bfbits2f(pr0.y) + EPS_PD, y1 = a[1] - bfbits2f(nr0.y) + EPS_PD;
                float x2 = a[2] - bfbits2f(pr0.z) + EPS_PD, y2 = a[2] - bfbits2f(nr0.z) + EPS_PD;
                float x3 = a[3] - bfbits2f(pr0.w) + EPS_PD, y3 = a[3] - bfbits2f(nr0.w) + EPS_PD;
                dp0 = x0 * x0 + x1 * x1 + x2 * x2 + x3 * x3;
                dn0 = y0 * y0 + y1 * y1 + y2 * y2 + y3 * y3;
            }
            {
                float x0 = a[0] - bfbits2f(pr1.x) + EPS_PD, y0 = a[0] - bfbits2f(nr1.x) + EPS_PD;
                float x1 = a[1] - bfbits2f(pr1.y) + EPS_PD, y1 = a[1] - bfbits2f(nr1.y) + EPS_PD;
                float x2 = a[2] - bfbits2f(pr1.z) + EPS_PD, y2 = a[2] - bfbits2f(nr1.z) + EPS_PD;
                float x3 = a[3] - bfbits2f(pr1.w) + EPS_PD, y3 = a[3] - bfbits2f(nr1.w) + EPS_PD;
                dp1 = x0 * x0 + x1 * x1 + x2 * x2 + x3 * x3;
                dn1 = y0 * y0 + y1 * y1 + y2 * y2 + y3 * y3;
            }
            #pragma unroll
            for (int st = 1; st <= 32; st <<= 1) {
                dp0 += __shfl_xor(dp0, st); dn0 += __shfl_xor(dn0, st);
                dp1 += __shfl_xor(dp1, st); dn1 += __shfl_xor(dn1, st);
            }
            float v0 = dp0 - dn0 + MARGIN; s += v0 > 0.f ? v0 : 0.f;
            float v1 = dp1 - dn1 + MARGIN; s += v1 > 0.f ? v1 : 0.f;
        }
        if (k < dg) {
            int jp = __shfl(ipv, k), jn = __shfl(igv, k);
            ushort4 pr = *(const ushort4*)&emb[(size_t)jp * D + lane * 4];
            ushort4 nr = *(const ushort4*)&emb[(size_t)jn * D + lane * 4];
            float x0 = a[0] - bfbits2f(pr.x) + EPS_PD, y0 = a[0] - bfbits2f(nr.x) + EPS_PD;
            float x1 = a[1] - bfbits2f(pr.y) + EPS_PD, y1 = a[1] - bfbits2f(nr.y) + EPS_PD;
            float x2 = a[2] - bfbits2f(pr.z) + EPS_PD, y2 = a[2] - bfbits2f(nr.z) + EPS_PD;
            float x3 = a[3] - bfbits2f(pr.w) + EPS_PD, y3 = a[3] - bfbits2f(nr.w) + EPS_PD;
            float dp = x0 * x0 + x1 * x1 + x2 * x2 + x3 * x3;
            float dn = y0 * y0 + y1 * y1 + y2 * y2 + y3 * y3;
            #pragma unroll
            for (int st = 1; st <= 32; st <<= 1) { dp += __shfl_xor(dp, st); dn += __shfl_xor(dn, st); }
            float v = dp - dn + MARGIN;
            s += v > 0.f ? v : 0.f;
        }
        if (lane == 0) nlpart[z * N + n] = s / (float)dg;
    }
}

// ---------------------------------------------------------------------------
// 4. proj2 GEMM with fused row-normalize: block = 16 rows × all 256 cols.
// ---------------------------------------------------------------------------
__global__ void __launch_bounds__(256)
gemm_w2_norm(const __hip_bfloat16* __restrict__ xbase,
             const __hip_bfloat16* __restrict__ conv,
             __hip_bfloat16* __restrict__ qbase) {
    int z = blockIdx.z;
    const __hip_bfloat16* A = xbase + (size_t)z * N * D;
    const __hip_bfloat16* B = conv + OFF_W2;
    __shared__ __align__(16) __hip_bfloat16 As[16 * LDP];
    __shared__ __align__(16) __hip_bfloat16 Bs[256 * LDP];
    __shared__ float sred[4][16];
    int bm = blockIdx.x * 16;
    int tid = threadIdx.x, wave = tid >> 6, lane = tid & 63;
    int quad = lane >> 4, l15 = lane & 15;
    int wc = wave * 64;
    facc4 acc[4] = {};
    for (int k0 = 0; k0 < D; k0 += 32) {
        if (tid < 64) {
            int r = tid >> 2, kq = (tid & 3) * 8;
            *(bfrag8*)&As[r * LDP + kq] = *(const bfrag8*)&A[(size_t)(bm + r) * D + k0 + kq];
        }
        #pragma unroll
        for (int i = 0; i < 4; i++) {
            int f = tid + 256 * i;          // 1024 fragments of B
            int r = f >> 2, kq = (f & 3) * 8;
            *(bfrag8*)&Bs[r * LDP + kq] = *(const bfrag8*)&B[(size_t)r * D + k0 + kq];
        }
        __syncthreads();
        bfrag8 af = *(const bfrag8*)&As[l15 * LDP + quad * 8];
        __builtin_amdgcn_s_setprio(1);
        #pragma unroll
        for (int ni = 0; ni < 4; ni++) {
            bfrag8 bf = *(const bfrag8*)&Bs[(wc + ni * 16 + l15) * LDP + quad * 8];
            acc[ni] = mfma16(af, bf, acc[ni]);
        }
        __builtin_amdgcn_s_setprio(0);
        __syncthreads();
    }
    float vv[4][4];   // [ni][r], bias applied
    #pragma unroll
    for (int ni = 0; ni < 4; ni++) {
        float bb = b2f(conv[OFF_B2 + wc + ni * 16 + l15]);
        #pragma unroll
        for (int r = 0; r < 4; r++) vv[ni][r] = acc[ni][r] + bb;
    }
    #pragma unroll
    for (int r = 0; r < 4; r++) {
        float ss = vv[0][r] * vv[0][r] + vv[1][r] * vv[1][r] +
                   vv[2][r] * vv[2][r] + vv[3][r] * vv[3][r];
        ss += __shfl_xor(ss, 1); ss += __shfl_xor(ss, 2);
        ss += __shfl_xor(ss, 4); ss += __shfl_xor(ss, 8);
        if (l15 == 0) sred[wave][quad * 4 + r] = ss;
    }
    __syncthreads();
    #pragma unroll
    for (int r = 0; r < 4; r++) {
        int rl = quad * 4 + r;
        float ssum = sred[0][rl] + sred[1][rl] + sred[2][rl] + sred[3][rl];
        float inv = rsqrtf(ssum + 1e-30f);
        int row = bm + rl;
        #pragma unroll
        for (int ni = 0; ni < 4; ni++)
            qbase[(size_t)z * N * D + (size_t)row * D + wc + ni * 16 + l15] =
                __float2bfloat16(vv[ni][r] * inv);
    }
}

// ---------------------------------------------------------------------------
// 5. FUSED sim + posdot + z_mp:
//    blockIdx.y<32:  sim MFMA 128x128 tile -> rowsum/colsum atomics
//    32<=y<64:       posdot for pair (gather, latency-bound)
//    y==64:          beta reduce (redundant per block) + z_mp output slice
// ---------------------------------------------------------------------------
__global__ void __launch_bounds__(256)
sim_pd_zmp(const __hip_bfloat16* __restrict__ q,
           float* __restrict__ rowsum, float* __restrict__ colsum,
           const __hip_bfloat16* __restrict__ embBase,
           const int* __restrict__ nbr_idx, const float* __restrict__ nbr_val,
           const int* __restrict__ deg,
           float* __restrict__ pdrow, float* __restrict__ pdcol,
           const float* __restrict__ spacc,
           const __hip_bfloat16* __restrict__ conv,
           const int* __restrict__ counter,
           void* __restrict__ out) {
    __shared__ __align__(16) __hip_bfloat16 As[128 * 64];
    __shared__ __align__(16) __hip_bfloat16 Bs[128 * 64];
    int pair = blockIdx.z;
    int y = blockIdx.y;
    if (y < 32) {
        const __hip_bfloat16* Qa = q + (size_t)pair * N * D;
        const __hip_bfloat16* Qb = q + (size_t)2 * N * D;
        int bm = blockIdx.x * 128, bn = y * 128;
        int tid = threadIdx.x, wave = tid >> 6, lane = tid & 63;
        int quad = lane >> 4, l15 = lane & 15;
        int wr = (wave & 1) * 64, wc = (wave >> 1) * 64;
        facc4 acc[4][4] = {};
        int sr0 = tid >> 3;                 // 0..31
        int cc  = tid & 7;                  // lds chunk slot
        for (int k0 = 0; k0 < D; k0 += 64) {
            #pragma unroll
            for (int i = 0; i < 4; i++) {
                int r = sr0 + 32 * i;
                int cg = (cc ^ (r & 7)) * 8;          // swizzled global chunk
                gl_lds16(&Qa[(size_t)(bm + r) * D + k0 + cg], &As[r * 64 + cc * 8]);
                gl_lds16(&Qb[(size_t)(bn + r) * D + k0 + cg], &Bs[r * 64 + cc * 8]);
            }
            __syncthreads();
            __builtin_amdgcn_s_setprio(1);
            #pragma unroll
            for (int kk = 0; kk < 64; kk += 32) {
                int kb = kk >> 3;
                bfrag8 af[4], bfr[4];
                #pragma unroll
                for (int mi = 0; mi < 4; mi++) {
                    int R = wr + mi * 16 + l15;
                    int pc = ((kb + quad) ^ (l15 & 7)) * 8;
                    af[mi] = *(const bfrag8*)&As[R * 64 + pc];
                }
                #pragma unroll
                for (int ni = 0; ni < 4; ni++) {
                    int R = wc + ni * 16 + l15;
                    int pc = ((kb + quad) ^ (l15 & 7)) * 8;
                    bfr[ni] = *(const bfrag8*)&Bs[R * 64 + pc];
                }
                #pragma unroll
                for (int mi = 0; mi < 4; mi++)
                    #pragma unroll
                    for (int ni = 0; ni < 4; ni++)
                        acc[mi][ni] = mfma16(af[mi], bfr[ni], acc[mi][ni]);
            }
            __builtin_amdgcn_s_setprio(0);
            __syncthreads();
        }
        constexpr float invtau = 1.0f / TAU;
        float rs[4][4];
        float cs[4] = {0.f, 0.f, 0.f, 0.f};
        #pragma unroll
        for (int mi = 0; mi < 4; mi++)
            #pragma unroll
            for (int r = 0; r < 4; r++) rs[mi][r] = 0.f;
        #pragma unroll
        for (int mi = 0; mi < 4; mi++)
            #pragma unroll
            for (int ni = 0; ni < 4; ni++)
                #pragma unroll
                for (int r = 0; r < 4; r++) {
                    float e = __expf(acc[mi][ni][r] * invtau);
                    rs[mi][r] += e;
                    cs[ni] += e;
                }
        #pragma unroll
        for (int mi = 0; mi < 4; mi++)
            #pragma unroll
            for (int r = 0; r < 4; r++) {
                float v = rs[mi][r];
                v += __shfl_xor(v, 1); v += __shfl_xor(v, 2);
                v += __shfl_xor(v, 4); v += __shfl_xor(v, 8);
                rs[mi][r] = v;
            }
        if (l15 == 0) {
            #pragma unroll
            for (int mi = 0; mi < 4; mi++)
                #pragma unroll
                for (int r = 0; r < 4; r++)
                    atomicAdd(&rowsum[(size_t)pair * N + bm + wr + mi * 16 + quad * 4 + r], rs[mi][r]);
        }
        #pragma unroll
        for (int ni = 0; ni < 4; ni++) {
            float v = cs[ni];
            v += __shfl_xor(v, 16); v += __shfl_xor(v, 32);
            if (quad == 0)
                atomicAdd(&colsum[(size_t)pair * N + bn + wc + ni * 16 + l15], v);
        }
    } else if (y < 64) {
        // ---- posdot for 4 nodes (one per wave)
        int wave = threadIdx.x >> 6, lane = threadIdx.x & 63;
        int nb = blockIdx.x * 32 + (y - 32);    // [0,1024)
        int n = nb * 4 + wave;
        const __hip_bfloat16* Qa = q + (size_t)pair * N * D;
        const __hip_bfloat16* Qb = q + (size_t)2 * N * D;
        int dg = deg[pair * N + n];
        int idxv = 0; float valv = 0.f;
        if (lane < MAXDEG) {
            idxv = nbr_idx[((size_t)pair * N + n) * MAXDEG + lane];
            valv = nbr_val[((size_t)pair * N + n) * MAXDEG + lane];
        }
        const float invtau = 1.0f / TAU;
        ushort4 ar = *(const ushort4*)&Qa[(size_t)n * D + lane * 4];
        ushort4 br = *(const ushort4*)&Qb[(size_t)n * D + lane * 4];
        float a[4] = {bfbits2f(ar.x), bfbits2f(ar.y), bfbits2f(ar.z), bfbits2f(ar.w)};
        float b[4] = {bfbits2f(br.x), bfbits2f(br.y), bfbits2f(br.z), bfbits2f(br.w)};
        float sr = 0.f, sc = 0.f;
        int k = 0;
        for (; k + 1 < dg; k += 2) {
            int j0 = __shfl(idxv, k), j1 = __shfl(idxv, k + 1);
            float vk0 = __shfl(valv, k), vk1 = __shfl(valv, k + 1);
            ushort4 pj0 = *(const ushort4*)&Qb[(size_t)j0 * D + lane * 4];
            ushort4 aj0 = *(const ushort4*)&Qa[(size_t)j0 * D + lane * 4];
            ushort4 pj1 = *(const ushort4*)&Qb[(size_t)j1 * D + lane * 4];
            ushort4 aj1 = *(const ushort4*)&Qa[(size_t)j1 * D + lane * 4];
            float dr0 = a[0] * bfbits2f(pj0.x) + a[1] * bfbits2f(pj0.y) +
                        a[2] * bfbits2f(pj0.z) + a[3] * bfbits2f(pj0.w);
            float dc0 = b[0] * bfbits2f(aj0.x) + b[1] * bfbits2f(aj0.y) +
                        b[2] * bfbits2f(aj0.z) + b[3] * bfbits2f(aj0.w);
            float dr1 = a[0] * bfbits2f(pj1.x) + a[1] * bfbits2f(pj1.y) +
                        a[2] * bfbits2f(pj1.z) + a[3] * bfbits2f(pj1.w);
            float dc1 = b[0] * bfbits2f(aj1.x) + b[1] * bfbits2f(aj1.y) +
                        b[2] * bfbits2f(aj1.z) + b[3] * bfbits2f(aj1.w);
            #pragma unroll
            for (int s2 = 1; s2 <= 32; s2 <<= 1) {
                dr0 += __shfl_xor(dr0, s2); dc0 += __shfl_xor(dc0, s2);
                dr1 += __shfl_xor(dr1, s2); dc1 += __shfl_xor(dc1, s2);
            }
            sr += __expf(dr0 * invtau) * vk0 + __expf(dr1 * invtau) * vk1;
            sc += __expf(dc0 * invtau) * vk0 + __expf(dc1 * invtau) * vk1;
        }
        if (k < dg) {
            int j = __shfl(idxv, k);
            float vk = __shfl(valv, k);
            ushort4 pj = *(const ushort4*)&Qb[(size_t)j * D + lane * 4];
            ushort4 aj = *(const ushort4*)&Qa[(size_t)j * D + lane * 4];
            float dr = a[0] * bfbits2f(pj.x) + a[1] * bfbits2f(pj.y) +
                       a[2] * bfbits2f(pj.z) + a[3] * bfbits2f(pj.w);
            float dc = b[0] * bfbits2f(aj.x) + b[1] * bfbits2f(aj.y) +
                       b[2] * bfbits2f(aj.z) + b[3] * bfbits2f(aj.w);
            #pragma unroll
            for (int s2 = 1; s2 <= 32; s2 <<= 1) { dr += __shfl_xor(dr, s2); dc += __shfl_xor(dc, s2); }
            sr += __expf(dr * invtau) * vk;
            sc += __expf(dc * invtau) * vk;
        }
        if (lane == 0) { pdrow[pair * N + n] = sr; pdcol[pair * N + n] = sc; }
    } else {
        // ---- beta (redundant reduce per block) + z_mp output slice
        int bf = get_bf(counter);
        int t = threadIdx.x;
        float* red = (float*)As;     // alias LDS
        float* w   = (float*)Bs;
        for (int p = 0; p < P; p++) {
            float v = (spacc[p * D + t] / (float)N) * b2f(conv[OFF_AV + t]);
            red[t] = v;
            __syncthreads();
            for (int s = 128; s > 0; s >>= 1) { if (t < s) red[t] += red[t + s]; __syncthreads(); }
            if (t == 0) w[p] = red[0];
            __syncthreads();
        }
        float m = fmaxf(w[0], fmaxf(w[1], w[2]));
        float e0 = __expf(w[0] - m), e1 = __expf(w[1] - m), e2 = __expf(w[2] - m);
        float ssum = e0 + e1 + e2;
        float b0 = e0 / ssum, b1 = e1 / ssum, b2 = e2 / ssum;
        int slice = pair * 32 + blockIdx.x;       // [0,64)
        int base = slice * (N * D / 64);
        for (int e = t * 4; e < N * D / 64; e += 256 * 4) {
            int i = base + e;
            ushort4 x0 = *(const ushort4*)&embBase[i];
            ushort4 x1 = *(const ushort4*)&embBase[(size_t)N * D + i];
            ushort4 x2 = *(const ushort4*)&embBase[(size_t)2 * N * D + i];
            float v[4];
            v[0] = b0 * bfbits2f(x0.x) + b1 * bfbits2f(x1.x) + b2 * bfbits2f(x2.x);
            v[1] = b0 * bfbits2f(x0.y) + b1 * bfbits2f(x1.y) + b2 * bfbits2f(x2.y);
            v[2] = b0 * bfbits2f(x0.z) + b1 * bfbits2f(x1.z) + b2 * bfbits2f(x2.z);
            v[3] = b0 * bfbits2f(x0.w) + b1 * bfbits2f(x1.w) + b2 * bfbits2f(x2.w);
            if (bf) {
                ushort4 ov;
                ov.x = f2bfbits(v[0]); ov.y = f2bfbits(v[1]);
                ov.z = f2bfbits(v[2]); ov.w = f2bfbits(v[3]);
                *(ushort4*)&((__hip_bfloat16*)out)[i] = ov;
            } else {
                float* o = (float*)out;
                o[i] = v[0]; o[i + 1] = v[1]; o[i + 2] = v[2]; o[i + 3] = v[3];
            }
        }
    }
}

// ---------------------------------------------------------------------------
// 6. finalize: single block -> loss reduce + write out[N*D].
// ---------------------------------------------------------------------------
__global__ void __launch_bounds__(256)
finalize_loss(const float* __restrict__ nlpart,
              const float* __restrict__ rowsum, const float* __restrict__ colsum,
              const float* __restrict__ pdrow, const float* __restrict__ pdcol,
              const int* __restrict__ counter,
              void* __restrict__ out) {
    int bf = get_bf(counter);
    int t = threadIdx.x;
    __shared__ float red[256];
    float s = 0.f;
    for (int i = t; i < P * N; i += 256) s += nlpart[i];
    for (int i = t; i < 2 * N; i += 256) {
        float l12 = -logf(pdrow[i] / (rowsum[i] + 1e-8f));
        float l21 = -logf(pdcol[i] / (colsum[i] + 1e-8f));
        s += (0.5f * l12 + 0.5f * l21) / (float)N;
    }
    red[t] = s;
    __syncthreads();
    for (int st = 128; st > 0; st >>= 1) { if (t < st) red[t] += red[t + st]; __syncthreads(); }
    if (t == 0) {
        if (bf) ((__hip_bfloat16*)out)[(size_t)N * D] = __float2bfloat16(red[0]);
        else    ((float*)out)[(size_t)N * D] = red[0];
    }
}

extern "C" void kernel_launch(void* const* d_in, const int* in_sizes, int n_in,
                              void* d_out, int out_size, void* d_ws, size_t ws_size,
                              hipStream_t stream) {
    const void* h        = d_in[0];
    const void* mps      = d_in[1];
    const void* W_gcn    = d_in[2];
    const void* b_gcn    = d_in[3];
    const void* prelu_a  = d_in[4];
    const void* att_fc_W = d_in[5];
    const void* att_fc_b = d_in[6];
    const void* att_vec  = d_in[7];
    const void* proj_W1  = d_in[8];
    const void* proj_b1  = d_in[9];
    const void* proj_W2  = d_in[10];
    const void* proj_b2  = d_in[11];

    char* ws = (char*)d_ws;
    size_t off = 0;
    auto alloc = [&](size_t bytes) -> char* {
        char* p = ws + off;
        off = (off + bytes + 255) & ~(size_t)255;
        return p;
    };
    __hip_bfloat16* conv = (__hip_bfloat16*)alloc((size_t)CONV_TOTAL * 2);
    __hip_bfloat16* xbuf = (__hip_bfloat16*)alloc((size_t)P * N * D * 2);
    __hip_bfloat16* emb  = (__hip_bfloat16*)alloc((size_t)P * N * D * 2);
    __hip_bfloat16* q    = (__hip_bfloat16*)alloc((size_t)P * N * D * 2);
    int*   nbr_idx = (int*)alloc((size_t)P * N * MAXDEG * 4);
    float* nbr_val = (float*)alloc((size_t)P * N * MAXDEG * 4);
    int*   neg_idx = (int*)alloc((size_t)P * N * MAXDEG * 4);
    int*   deg     = (int*)alloc((size_t)P * N * 4);
    float* nlpart  = (float*)alloc((size_t)P * N * 4);
    float* pdrow   = (float*)alloc((size_t)2 * N * 4);
    float* pdcol   = (float*)alloc((size_t)2 * N * 4);
    char* zero_begin = ws + off;
    float* rowsum = (float*)alloc((size_t)2 * N * 4);
    float* colsum = (float*)alloc((size_t)2 * N * 4);
    float* spacc  = (float*)alloc((size_t)P * D * 4);
    size_t zero_bytes = (size_t)((ws + off) - zero_begin);
    int*   counter = (int*)alloc(16);   // NOT zeroed: detect uses atomicMax sentinel

    // 0. dtype detection + zero the atomic-accumulator region (one dispatch)
    detect_dtype<<<1024, 256, 0, stream>>>((const unsigned int*)mps, 2 * 1024 * 1024,
                                           counter, (float*)zero_begin,
                                           (int)(zero_bytes / 4));

    // 1. fused: triple GEMM (raw h/Wg) + sparse extraction + small-weight convert
    stage2<<<256 + P * N + 64, 256, 0, stream>>>(h, W_gcn, mps,
                                                 att_fc_W, proj_W1, proj_W2, b_gcn,
                                                 att_fc_b, att_vec, prelu_a, proj_b1, proj_b2,
                                                 counter, conv, xbuf,
                                                 nbr_idx, nbr_val, neg_idx, deg);

    // 2. emb[z] = prelu(spmm + bias)
    spmm_prelu<<<dim3(N / 4, 1, P), 256, 0, stream>>>(xbuf, nbr_idx, nbr_val, deg, conv, emb);

    // 3. fused: spacc/elu GEMM + node loss
    gemm_dual_nl<<<dim3(64, 20, P), 256, 0, stream>>>(emb, conv, xbuf, spacc,
                                                      nbr_idx, neg_idx, deg, nlpart);

    // 4. q[z] = rownorm(xbuf[z] @ W2^T + b2), fused
    gemm_w2_norm<<<dim3(N / 16, 1, P), 256, 0, stream>>>(xbuf, conv, q);

    // 5. fused: sim rowsum/colsum + posdot + beta/z_mp output
    sim_pd_zmp<<<dim3(32, 65, 2), 256, 0, stream>>>(q, rowsum, colsum, emb,
                                                    nbr_idx, nbr_val, deg,
                                                    pdrow, pdcol, spacc, conv,
                                                    counter, d_out);

    // 6. finalize: loss scalar
    finalize_loss<<<1, 256, 0, stream>>>(nlpart, rowsum, colsum, pdrow, pdcol,
                                         counter, d_out);
}

// Round 8
// 440.079 us; speedup vs baseline: 1.0767x; 1.0751x over previous
//
#include <hip/hip_runtime.h>
#include <hip/hip_bf16.h>

// Problem constants (Mp_encoder): N nodes, D dims, P metapaths.
constexpr int N = 4096;
constexpr int D = 256;
constexpr int P = 3;
constexpr int MAXDEG = 17;       // K+1
constexpr float TAU = 0.8f;
constexpr float MARGIN = 0.1f;
constexpr float EPS_PD = 1e-6f;

constexpr int LDP = 40;          // LDS k-stride for 64-tiles (2-way max conflicts)

// bf16 conversion-area offsets (elements), all 256-aligned
constexpr int OFF_ATTW = 1245184;       // 65536
constexpr int OFF_W1   = 1310720;       // 65536
constexpr int OFF_W2   = 1376256;       // 65536
constexpr int OFF_BG   = 1441792;       // 768
constexpr int OFF_ATTB = 1442560;       // 256
constexpr int OFF_AV   = 1442816;       // 256
constexpr int OFF_PA   = 1443072;       // 3 (reserve 256)
constexpr int OFF_B1   = 1443328;       // 256
constexpr int OFF_B2   = 1443584;       // 256
constexpr int CONV_TOTAL = 1443840;

typedef __attribute__((ext_vector_type(8))) short bfrag8;
typedef __attribute__((ext_vector_type(4))) float facc4;

__device__ inline facc4 mfma16(bfrag8 a, bfrag8 b, facc4 c) {
    return __builtin_amdgcn_mfma_f32_16x16x32_bf16(a, b, c, 0, 0, 0);
}
__device__ inline float b2f(__hip_bfloat16 v) { return __bfloat162float(v); }
__device__ inline float bfbits2f(unsigned short u) {
    return __uint_as_float(((unsigned int)u) << 16);
}
__device__ inline unsigned short f2bfbits(float v) {
    __hip_bfloat16 t = __float2bfloat16(v);
    return *(unsigned short*)&t;
}
__device__ inline int get_bf(const int* __restrict__ counter) { return counter[0] > 100; }

__device__ inline float load_in(const void* p, size_t i, int bf) {
    return bf ? __bfloat162float(((const __hip_bfloat16*)p)[i])
              : ((const float*)p)[i];
}

// async global->LDS, 16 bytes per lane; dest = wave-uniform base + lane*16
__device__ __forceinline__ void gl_lds16(const __hip_bfloat16* g, __hip_bfloat16* l) {
    __builtin_amdgcn_global_load_lds(
        (const __attribute__((address_space(1))) unsigned int*)g,
        (__attribute__((address_space(3))) unsigned int*)l, 16, 0, 0);
}

// ---------------------------------------------------------------------------
// 0. dtype detection (atomicMax sentinel) + zero atomic-accumulator region.
//    Sample 1 MB of mps (plenty: ~65 fp32 rows / ~131 bf16 rows, each with
//    ~17 sparse nonzeros).
// ---------------------------------------------------------------------------
__global__ void __launch_bounds__(256)
detect_dtype(const unsigned int* __restrict__ w, int nwords,
             int* __restrict__ counter,
             float* __restrict__ zbuf, int nz) {
    int t0 = blockIdx.x * blockDim.x + threadIdx.x;
    int stride = gridDim.x * blockDim.x;
    for (int i = t0; i < nz; i += stride) zbuf[i] = 0.f;
    int c = 0;
    for (int i = t0; i < nwords; i += stride) {
        unsigned int x = w[i];
        if ((x & 0xFFFF0000u) == 0u && x != 0u) c++;
    }
    for (int s = 32; s > 0; s >>= 1) c += __shfl_down(c, s);
    if ((threadIdx.x & 63) == 0 && c > 0) atomicMax(counter, 1 << 20);
}

// ---------------------------------------------------------------------------
// 1. FUSED stage2: one dispatch =
//    blocks [0,256):          triple-B GCN GEMM reading RAW h / W_gcn
//    blocks [256,256+P*N):    sparse extraction (per (p,n) row of mps)
//    blocks [256+P*N, +64):   convert small dense weights to bf16 staging
// ---------------------------------------------------------------------------
__global__ void __launch_bounds__(256)
stage2(const void* __restrict__ h, const void* __restrict__ wg,
       const void* __restrict__ mps,
       const void* attw, const void* w1, const void* w2,
       const void* bg, const void* attb, const void* av,
       const void* pa, const void* b1, const void* b2,
       const int* __restrict__ counter,
       __hip_bfloat16* __restrict__ conv,
       __hip_bfloat16* __restrict__ xbuf,
       int* __restrict__ nbr_idx, float* __restrict__ nbr_val,
       int* __restrict__ neg_idx, int* __restrict__ deg) {
    __shared__ __align__(16) __hip_bfloat16 As[64 * LDP];
    __shared__ __align__(16) __hip_bfloat16 Bs[3][64 * LDP];
    int bid = blockIdx.x;
    int bf = get_bf(counter);
    if (bid < 256) {
        // ---- triple GEMM: X[z] = h @ Wg[z]^T, raw-input in-register convert
        int bm = (bid & 63) * 64, bn = (bid >> 6) * 64;
        int tid = threadIdx.x, wave = tid >> 6, lane = tid & 63;
        int quad = lane >> 4, l15 = lane & 15;
        int wr = (wave & 1) * 32, wc = (wave >> 1) * 32;
        facc4 acc[3][2][2] = {};
        int sr = tid >> 2, kq = (tid & 3) * 8;
        for (int k0 = 0; k0 < D; k0 += 32) {
            if (bf) {
                *(bfrag8*)&As[sr * LDP + kq] =
                    *(const bfrag8*)((const unsigned short*)h + (size_t)(bm + sr) * D + k0 + kq);
                #pragma unroll
                for (int z = 0; z < 3; z++)
                    *(bfrag8*)&Bs[z][sr * LDP + kq] =
                        *(const bfrag8*)((const unsigned short*)wg +
                                         (size_t)z * D * D + (size_t)(bn + sr) * D + k0 + kq);
            } else {
                const float* hp = (const float*)h + (size_t)(bm + sr) * D + k0 + kq;
                float4 a0 = *(const float4*)hp, a1 = *(const float4*)(hp + 4);
                bfrag8 t;
                t[0] = f2bfbits(a0.x); t[1] = f2bfbits(a0.y);
                t[2] = f2bfbits(a0.z); t[3] = f2bfbits(a0.w);
                t[4] = f2bfbits(a1.x); t[5] = f2bfbits(a1.y);
                t[6] = f2bfbits(a1.z); t[7] = f2bfbits(a1.w);
                *(bfrag8*)&As[sr * LDP + kq] = t;
                #pragma unroll
                for (int z = 0; z < 3; z++) {
                    const float* wp = (const float*)wg +
                        (size_t)z * D * D + (size_t)(bn + sr) * D + k0 + kq;
                    float4 b0 = *(const float4*)wp, b1v = *(const float4*)(wp + 4);
                    bfrag8 u;
                    u[0] = f2bfbits(b0.x);  u[1] = f2bfbits(b0.y);
                    u[2] = f2bfbits(b0.z);  u[3] = f2bfbits(b0.w);
                    u[4] = f2bfbits(b1v.x); u[5] = f2bfbits(b1v.y);
                    u[6] = f2bfbits(b1v.z); u[7] = f2bfbits(b1v.w);
                    *(bfrag8*)&Bs[z][sr * LDP + kq] = u;
                }
            }
            __syncthreads();
            bfrag8 af[2];
            #pragma unroll
            for (int mi = 0; mi < 2; mi++)
                af[mi] = *(const bfrag8*)&As[(wr + mi * 16 + l15) * LDP + quad * 8];
            #pragma unroll
            for (int z = 0; z < 3; z++) {
                bfrag8 bfr[2];
                #pragma unroll
                for (int ni = 0; ni < 2; ni++)
                    bfr[ni] = *(const bfrag8*)&Bs[z][(wc + ni * 16 + l15) * LDP + quad * 8];
                #pragma unroll
                for (int mi = 0; mi < 2; mi++)
                    #pragma unroll
                    for (int ni = 0; ni < 2; ni++)
                        acc[z][mi][ni] = mfma16(af[mi], bfr[ni], acc[z][mi][ni]);
            }
            __syncthreads();
        }
        #pragma unroll
        for (int z = 0; z < 3; z++)
            #pragma unroll
            for (int mi = 0; mi < 2; mi++)
                #pragma unroll
                for (int ni = 0; ni < 2; ni++) {
                    int col = bn + wc + ni * 16 + l15;
                    #pragma unroll
                    for (int r = 0; r < 4; r++) {
                        int row = bm + wr + mi * 16 + quad * 4 + r;
                        xbuf[(size_t)z * N * D + (size_t)row * D + col] =
                            __float2bfloat16(acc[z][mi][ni][r]);
                    }
                }
    } else if (bid < 256 + P * N) {
        // ---- sparse extraction for row (p,n); LDS aliased onto As
        int row = bid - 256;
        int t = threadIdx.x;
        int* cnt = (int*)As;
        int* sidx = ((int*)As) + 1;
        float* sval = (float*)(((int*)As) + 33);
        if (t == 0) *cnt = 0;
        __syncthreads();
        int e0 = t * 16;
        if (bf) {
            const uint4* base = (const uint4*)((const __hip_bfloat16*)mps + (size_t)row * N + e0);
            #pragma unroll
            for (int v = 0; v < 2; v++) {
                uint4 w = base[v];
                unsigned int ws[4] = {w.x, w.y, w.z, w.w};
                #pragma unroll
                for (int j = 0; j < 4; j++) {
                    unsigned short lo = (unsigned short)(ws[j] & 0xFFFFu);
                    unsigned short hi = (unsigned short)(ws[j] >> 16);
                    if (lo) { int k = atomicAdd(cnt, 1); if (k < 32) { sidx[k] = e0 + v * 8 + j * 2;     sval[k] = bfbits2f(lo); } }
                    if (hi) { int k = atomicAdd(cnt, 1); if (k < 32) { sidx[k] = e0 + v * 8 + j * 2 + 1; sval[k] = bfbits2f(hi); } }
                }
            }
        } else {
            const float4* base = (const float4*)((const float*)mps + (size_t)row * N + e0);
            #pragma unroll
            for (int v = 0; v < 4; v++) {
                float4 w = base[v];
                float ws[4] = {w.x, w.y, w.z, w.w};
                #pragma unroll
                for (int j = 0; j < 4; j++)
                    if (ws[j] > 0.f) { int k = atomicAdd(cnt, 1); if (k < 32) { sidx[k] = e0 + v * 4 + j; sval[k] = ws[j]; } }
            }
        }
        __syncthreads();
        if (t < 64) {
            int dg = *cnt; if (dg > MAXDEG) dg = MAXDEG;
            int myidx = 0; float myval = 0.f; int rank = 0;
            if (t < dg) {
                myidx = sidx[t]; myval = sval[t];
                for (int j = 0; j < dg; j++) rank += (sidx[j] < myidx) ? 1 : 0;
            }
            if (t < dg) { sidx[rank] = myidx; sval[rank] = myval; }
            if (t < MAXDEG) {
                nbr_idx[(size_t)row * MAXDEG + t] = (t < dg) ? sidx[t] : 0;
                nbr_val[(size_t)row * MAXDEG + t] = (t < dg) ? sval[t] : 0.f;
            }
            if (t == 0) deg[row] = dg;
            int c = t;
            bool cand = (c < dg + MAXDEG);
            bool isnbr = false;
            if (cand) for (int j = 0; j < dg; j++) isnbr |= (sidx[j] == c);
            bool nonnbr = cand && !isnbr;
            unsigned long long m = __ballot(nonnbr);
            int nrank = __popcll(m & ((c < 64) ? ((1ull << c) - 1ull) : ~0ull));
            if (nonnbr && nrank < MAXDEG) neg_idx[(size_t)row * MAXDEG + nrank] = c;
        }
    } else {
        // ---- convert small dense weights (h/W_gcn no longer staged)
        int cb = bid - (256 + P * N);
        const void* srcs[9] = {attw, w1, w2, bg, attb, av, pa, b1, b2};
        const int offs[9] = {OFF_ATTW, OFF_W1, OFF_W2, OFF_BG, OFF_ATTB,
                             OFF_AV, OFF_PA, OFF_B1, OFF_B2};
        const int lens[9] = {65536, 65536, 65536, 768, 256, 256, 3, 256, 256};
        int stride = 64 * 256;
        int t0 = cb * 256 + threadIdx.x;
        #pragma unroll
        for (int s = 0; s < 9; s++) {
            for (int i = t0; i < lens[s]; i += stride)
                conv[offs[s] + i] = __float2bfloat16(load_in(srcs[s], i, bf));
        }
    }
}

// ---------------------------------------------------------------------------
// 2. spmm + prelu: wave per node, idx/val in lane registers, 4-way unroll.
// ---------------------------------------------------------------------------
__global__ void __launch_bounds__(256)
spmm_prelu(const __hip_bfloat16* __restrict__ Xbase,
           const int* __restrict__ nbr_idx, const float* __restrict__ nbr_val,
           const int* __restrict__ deg, const __hip_bfloat16* __restrict__ conv,
           __hip_bfloat16* __restrict__ embBase) {
    int z = blockIdx.z;
    int wave = threadIdx.x >> 6, lane = threadIdx.x & 63;
    int n = blockIdx.x * 4 + wave;
    const __hip_bfloat16* X = Xbase + (size_t)z * N * D;
    int dg = deg[z * N + n];
    int idxv = 0; float valv = 0.f;
    if (lane < MAXDEG) {
        idxv = nbr_idx[((size_t)z * N + n) * MAXDEG + lane];
        valv = nbr_val[((size_t)z * N + n) * MAXDEG + lane];
    }
    float acc[4] = {0.f, 0.f, 0.f, 0.f};
    int k = 0;
    for (; k + 3 < dg; k += 4) {
        int j0 = __shfl(idxv, k), j1 = __shfl(idxv, k + 1);
        int j2 = __shfl(idxv, k + 2), j3 = __shfl(idxv, k + 3);
        float v0 = __shfl(valv, k), v1 = __shfl(valv, k + 1);
        float v2 = __shfl(valv, k + 2), v3 = __shfl(valv, k + 3);
        ushort4 x0 = *(const ushort4*)&X[(size_t)j0 * D + lane * 4];
        ushort4 x1 = *(const ushort4*)&X[(size_t)j1 * D + lane * 4];
        ushort4 x2 = *(const ushort4*)&X[(size_t)j2 * D + lane * 4];
        ushort4 x3 = *(const ushort4*)&X[(size_t)j3 * D + lane * 4];
        acc[0] += v0 * bfbits2f(x0.x) + v1 * bfbits2f(x1.x) + v2 * bfbits2f(x2.x) + v3 * bfbits2f(x3.x);
        acc[1] += v0 * bfbits2f(x0.y) + v1 * bfbits2f(x1.y) + v2 * bfbits2f(x2.y) + v3 * bfbits2f(x3.y);
        acc[2] += v0 * bfbits2f(x0.z) + v1 * bfbits2f(x1.z) + v2 * bfbits2f(x2.z) + v3 * bfbits2f(x3.z);
        acc[3] += v0 * bfbits2f(x0.w) + v1 * bfbits2f(x1.w) + v2 * bfbits2f(x2.w) + v3 * bfbits2f(x3.w);
    }
    for (; k < dg; k++) {
        int j0 = __shfl(idxv, k); float v0 = __shfl(valv, k);
        ushort4 x0 = *(const ushort4*)&X[(size_t)j0 * D + lane * 4];
        acc[0] += v0 * bfbits2f(x0.x); acc[1] += v0 * bfbits2f(x0.y);
        acc[2] += v0 * bfbits2f(x0.z); acc[3] += v0 * bfbits2f(x0.w);
    }
    ushort4 bb = *(const ushort4*)&conv[OFF_BG + z * D + lane * 4];
    float a = b2f(conv[OFF_PA + z]);
    ushort4 o;
    float v0 = acc[0] + bfbits2f(bb.x); o.x = f2bfbits(v0 > 0.f ? v0 : a * v0);
    float v1 = acc[1] + bfbits2f(bb.y); o.y = f2bfbits(v1 > 0.f ? v1 : a * v1);
    float v2 = acc[2] + bfbits2f(bb.z); o.z = f2bfbits(v2 > 0.f ? v2 : a * v2);
    float v3 = acc[3] + bfbits2f(bb.w); o.w = f2bfbits(v3 > 0.f ? v3 : a * v3);
    *(ushort4*)&embBase[(size_t)z * N * D + (size_t)n * D + lane * 4] = o;
}

// ---------------------------------------------------------------------------
// 3. FUSED dual-B GEMM + node loss:
//    blockIdx.y<4: attention colsum path + elu(W1) path (MFMA-bound)
//    blockIdx.y>=4: node loss on emb[z] (gather/shfl latency-bound)
// ---------------------------------------------------------------------------
__global__ void __launch_bounds__(256)
gemm_dual_nl(const __hip_bfloat16* __restrict__ embBase,
             const __hip_bfloat16* __restrict__ conv,
             __hip_bfloat16* __restrict__ xbuf,
             float* __restrict__ spacc,
             const int* __restrict__ nbr_idx,
             const int* __restrict__ neg_idx,
             const int* __restrict__ deg,
             float* __restrict__ nlpart) {
    __shared__ __align__(16) __hip_bfloat16 As[64 * LDP];
    __shared__ __align__(16) __hip_bfloat16 Bsa[64 * LDP];
    __shared__ __align__(16) __hip_bfloat16 Bsw[64 * LDP];
    int z = blockIdx.z;
    if (blockIdx.y < 4) {
        const __hip_bfloat16* A = embBase + (size_t)z * N * D;
        const __hip_bfloat16* Ba = conv + OFF_ATTW;
        const __hip_bfloat16* Bw = conv + OFF_W1;
        int bm = blockIdx.x * 64, bn = blockIdx.y * 64;
        int tid = threadIdx.x, wave = tid >> 6, lane = tid & 63;
        int quad = lane >> 4, l15 = lane & 15;
        int wr = (wave & 1) * 32, wc = (wave >> 1) * 32;
        facc4 accA[2][2] = {};
        facc4 accW[2][2] = {};
        int sr = tid >> 2, kq = (tid & 3) * 8;
        for (int k0 = 0; k0 < D; k0 += 32) {
            *(bfrag8*)&As[sr * LDP + kq]  = *(const bfrag8*)&A[(size_t)(bm + sr) * D + k0 + kq];
            *(bfrag8*)&Bsa[sr * LDP + kq] = *(const bfrag8*)&Ba[(size_t)(bn + sr) * D + k0 + kq];
            *(bfrag8*)&Bsw[sr * LDP + kq] = *(const bfrag8*)&Bw[(size_t)(bn + sr) * D + k0 + kq];
            __syncthreads();
            bfrag8 af[2], ba[2], bw[2];
            #pragma unroll
            for (int mi = 0; mi < 2; mi++)
                af[mi] = *(const bfrag8*)&As[(wr + mi * 16 + l15) * LDP + quad * 8];
            #pragma unroll
            for (int ni = 0; ni < 2; ni++) {
                ba[ni] = *(const bfrag8*)&Bsa[(wc + ni * 16 + l15) * LDP + quad * 8];
                bw[ni] = *(const bfrag8*)&Bsw[(wc + ni * 16 + l15) * LDP + quad * 8];
            }
            #pragma unroll
            for (int mi = 0; mi < 2; mi++)
                #pragma unroll
                for (int ni = 0; ni < 2; ni++) {
                    accA[mi][ni] = mfma16(af[mi], ba[ni], accA[mi][ni]);
                    accW[mi][ni] = mfma16(af[mi], bw[ni], accW[mi][ni]);
                }
            __syncthreads();
        }
        float cs[2] = {0.f, 0.f};
        #pragma unroll
        for (int mi = 0; mi < 2; mi++) {
            #pragma unroll
            for (int ni = 0; ni < 2; ni++) {
                int col = bn + wc + ni * 16 + l15;
                float battb = b2f(conv[OFF_ATTB + col]);
                float bb1   = b2f(conv[OFF_B1 + col]);
                #pragma unroll
                for (int r = 0; r < 4; r++) {
                    int row = bm + wr + mi * 16 + quad * 4 + r;
                    cs[ni] += tanhf(accA[mi][ni][r] + battb);
                    float v = accW[mi][ni][r] + bb1;
                    v = v > 0.f ? v : expm1f(v);
                    xbuf[(size_t)z * N * D + (size_t)row * D + col] = __float2bfloat16(v);
                }
            }
        }
        #pragma unroll
        for (int ni = 0; ni < 2; ni++) {
            float v = cs[ni];
            v += __shfl_xor(v, 16); v += __shfl_xor(v, 32);
            if (quad == 0) {
                int col = bn + wc + ni * 16 + l15;
                atomicAdd(&spacc[(size_t)z * D + col], v);
            }
        }
    } else {
        // ---- node loss for 4 nodes (one per wave)
        int wave = threadIdx.x >> 6, lane = threadIdx.x & 63;
        int nb = blockIdx.x * 16 + (blockIdx.y - 4);   // [0,1024)
        int n = nb * 4 + wave;
        const __hip_bfloat16* emb = embBase + (size_t)z * N * D;
        int dg = deg[z * N + n];
        int ipv = 0, igv = 0;
        if (lane < MAXDEG) {
            ipv = nbr_idx[((size_t)z * N + n) * MAXDEG + lane];
            igv = neg_idx[((size_t)z * N + n) * MAXDEG + lane];
        }
        ushort4 ar = *(const ushort4*)&emb[(size_t)n * D + lane * 4];
        float a[4] = {bfbits2f(ar.x), bfbits2f(ar.y), bfbits2f(ar.z), bfbits2f(ar.w)};
        float s = 0.f;
        int k = 0;
        for (; k + 1 < dg; k += 2) {
            int jp0 = __shfl(ipv, k), jn0 = __shfl(igv, k);
            int jp1 = __shfl(ipv, k + 1), jn1 = __shfl(igv, k + 1);
            ushort4 pr0 = *(const ushort4*)&emb[(size_t)jp0 * D + lane * 4];
            ushort4 nr0 = *(const ushort4*)&emb[(size_t)jn0 * D + lane * 4];
            ushort4 pr1 = *(const ushort4*)&emb[(size_t)jp1 * D + lane * 4];
            ushort4 nr1 = *(const ushort4*)&emb[(size_t)jn1 * D + lane * 4];
            float dp0, dn0, dp1, dn1;
            {
                float x0 = a[0] - bfbits2f(pr0.x) + EPS_PD, y0 = a[0] - bfbits2f(nr0.x) + EPS_PD;
                float x1 = a[1] - bfbits2f(pr0.y) + EPS_PD, y1 = a[1] - bfbits2f(nr0.y) + EPS_PD;
                float x2 = a[2] - bfbits2f(pr0.z) + EPS_PD, y2 = a[2] - bfbits2f(nr0.z) + EPS_PD;
                float x3 = a[3] - bfbits2f(pr0.w) + EPS_PD, y3 = a[3] - bfbits2f(nr0.w) + EPS_PD;
                dp0 = x0 * x0 + x1 * x1 + x2 * x2 + x3 * x3;
                dn0 = y0 * y0 + y1 * y1 + y2 * y2 + y3 * y3;
            }
            {
                float x0 = a[0] - bfbits2f(pr1.x) + EPS_PD, y0 = a[0] - bfbits2f(nr1.x) + EPS_PD;
                float x1 = a[1] - bfbits2f(pr1.y) + EPS_PD, y1 = a[1] - bfbits2f(nr1.y) + EPS_PD;
                float x2 = a[2] - bfbits2f(pr1.z) + EPS_PD, y2 = a[2] - bfbits2f(nr1.z) + EPS_PD;
                float x3 = a[3] - bfbits2f(pr1.w) + EPS_PD, y3 = a[3] - bfbits2f(nr1.w) + EPS_PD;
                dp1 = x0 * x0 + x1 * x1 + x2 * x2 + x3 * x3;
                dn1 = y0 * y0 + y1 * y1 + y2 * y2 + y3 * y3;
            }
            #pragma unroll
            for (int st = 1; st <= 32; st <<= 1) {
                dp0 += __shfl_xor(dp0, st); dn0 += __shfl_xor(dn0, st);
                dp1 += __shfl_xor(dp1, st); dn1 += __shfl_xor(dn1, st);
            }
            float v0 = dp0 - dn0 + MARGIN; s += v0 > 0.f ? v0 : 0.f;
            float v1 = dp1 - dn1 + MARGIN; s += v1 > 0.f ? v1 : 0.f;
        }
        if (k < dg) {
            int jp = __shfl(ipv, k), jn = __shfl(igv, k);
            ushort4 pr = *(const ushort4*)&emb[(size_t)jp * D + lane * 4];
            ushort4 nr = *(const ushort4*)&emb[(size_t)jn * D + lane * 4];
            float x0 = a[0] - bfbits2f(pr.x) + EPS_PD, y0 = a[0] - bfbits2f(nr.x) + EPS_PD;
            float x1 = a[1] - bfbits2f(pr.y) + EPS_PD, y1 = a[1] - bfbits2f(nr.y) + EPS_PD;
            float x2 = a[2] - bfbits2f(pr.z) + EPS_PD, y2 = a[2] - bfbits2f(nr.z) + EPS_PD;
            float x3 = a[3] - bfbits2f(pr.w) + EPS_PD, y3 = a[3] - bfbits2f(nr.w) + EPS_PD;
            float dp = x0 * x0 + x1 * x1 + x2 * x2 + x3 * x3;
            float dn = y0 * y0 + y1 * y1 + y2 * y2 + y3 * y3;
            #pragma unroll
            for (int st = 1; st <= 32; st <<= 1) { dp += __shfl_xor(dp, st); dn += __shfl_xor(dn, st); }
            float v = dp - dn + MARGIN;
            s += v > 0.f ? v : 0.f;
        }
        if (lane == 0) nlpart[z * N + n] = s / (float)dg;
    }
}

// ---------------------------------------------------------------------------
// 4. proj2 GEMM with fused row-normalize: block = 16 rows × all 256 cols.
// ---------------------------------------------------------------------------
__global__ void __launch_bounds__(256)
gemm_w2_norm(const __hip_bfloat16* __restrict__ xbase,
             const __hip_bfloat16* __restrict__ conv,
             __hip_bfloat16* __restrict__ qbase) {
    int z = blockIdx.z;
    const __hip_bfloat16* A = xbase + (size_t)z * N * D;
    const __hip_bfloat16* B = conv + OFF_W2;
    __shared__ __align__(16) __hip_bfloat16 As[16 * LDP];
    __shared__ __align__(16) __hip_bfloat16 Bs[256 * LDP];
    __shared__ float sred[4][16];
    int bm = blockIdx.x * 16;
    int tid = threadIdx.x, wave = tid >> 6, lane = tid & 63;
    int quad = lane >> 4, l15 = lane & 15;
    int wc = wave * 64;
    facc4 acc[4] = {};
    for (int k0 = 0; k0 < D; k0 += 32) {
        if (tid < 64) {
            int r = tid >> 2, kq = (tid & 3) * 8;
            *(bfrag8*)&As[r * LDP + kq] = *(const bfrag8*)&A[(size_t)(bm + r) * D + k0 + kq];
        }
        #pragma unroll
        for (int i = 0; i < 4; i++) {
            int f = tid + 256 * i;          // 1024 fragments of B
            int r = f >> 2, kq = (f & 3) * 8;
            *(bfrag8*)&Bs[r * LDP + kq] = *(const bfrag8*)&B[(size_t)r * D + k0 + kq];
        }
        __syncthreads();
        bfrag8 af = *(const bfrag8*)&As[l15 * LDP + quad * 8];
        #pragma unroll
        for (int ni = 0; ni < 4; ni++) {
            bfrag8 bf = *(const bfrag8*)&Bs[(wc + ni * 16 + l15) * LDP + quad * 8];
            acc[ni] = mfma16(af, bf, acc[ni]);
        }
        __syncthreads();
    }
    float vv[4][4];   // [ni][r], bias applied
    #pragma unroll
    for (int ni = 0; ni < 4; ni++) {
        float bb = b2f(conv[OFF_B2 + wc + ni * 16 + l15]);
        #pragma unroll
        for (int r = 0; r < 4; r++) vv[ni][r] = acc[ni][r] + bb;
    }
    #pragma unroll
    for (int r = 0; r < 4; r++) {
        float ss = vv[0][r] * vv[0][r] + vv[1][r] * vv[1][r] +
                   vv[2][r] * vv[2][r] + vv[3][r] * vv[3][r];
        ss += __shfl_xor(ss, 1); ss += __shfl_xor(ss, 2);
        ss += __shfl_xor(ss, 4); ss += __shfl_xor(ss, 8);
        if (l15 == 0) sred[wave][quad * 4 + r] = ss;
    }
    __syncthreads();
    #pragma unroll
    for (int r = 0; r < 4; r++) {
        int rl = quad * 4 + r;
        float ssum = sred[0][rl] + sred[1][rl] + sred[2][rl] + sred[3][rl];
        float inv = rsqrtf(ssum + 1e-30f);
        int row = bm + rl;
        #pragma unroll
        for (int ni = 0; ni < 4; ni++)
            qbase[(size_t)z * N * D + (size_t)row * D + wc + ni * 16 + l15] =
                __float2bfloat16(vv[ni][r] * inv);
    }
}

// ---------------------------------------------------------------------------
// 5. FUSED sim + posdot + z_mp:
//    blockIdx.y<32:  sim MFMA 128x128 tile -> rowsum/colsum atomics
//    32<=y<64:       posdot for pair (gather, latency-bound)
//    y==64:          beta reduce (redundant per block) + z_mp output slice
// ---------------------------------------------------------------------------
__global__ void __launch_bounds__(256)
sim_pd_zmp(const __hip_bfloat16* __restrict__ q,
           float* __restrict__ rowsum, float* __restrict__ colsum,
           const __hip_bfloat16* __restrict__ embBase,
           const int* __restrict__ nbr_idx, const float* __restrict__ nbr_val,
           const int* __restrict__ deg,
           float* __restrict__ pdrow, float* __restrict__ pdcol,
           const float* __restrict__ spacc,
           const __hip_bfloat16* __restrict__ conv,
           const int* __restrict__ counter,
           void* __restrict__ out) {
    __shared__ __align__(16) __hip_bfloat16 As[128 * 64];
    __shared__ __align__(16) __hip_bfloat16 Bs[128 * 64];
    int pair = blockIdx.z;
    int y = blockIdx.y;
    if (y < 32) {
        const __hip_bfloat16* Qa = q + (size_t)pair * N * D;
        const __hip_bfloat16* Qb = q + (size_t)2 * N * D;
        int bm = blockIdx.x * 128, bn = y * 128;
        int tid = threadIdx.x, wave = tid >> 6, lane = tid & 63;
        int quad = lane >> 4, l15 = lane & 15;
        int wr = (wave & 1) * 64, wc = (wave >> 1) * 64;
        facc4 acc[4][4] = {};
        int sr0 = tid >> 3;                 // 0..31
        int cc  = tid & 7;                  // lds chunk slot
        for (int k0 = 0; k0 < D; k0 += 64) {
            #pragma unroll
            for (int i = 0; i < 4; i++) {
                int r = sr0 + 32 * i;
                int cg = (cc ^ (r & 7)) * 8;          // swizzled global chunk
                gl_lds16(&Qa[(size_t)(bm + r) * D + k0 + cg], &As[r * 64 + cc * 8]);
                gl_lds16(&Qb[(size_t)(bn + r) * D + k0 + cg], &Bs[r * 64 + cc * 8]);
            }
            __syncthreads();
            #pragma unroll
            for (int kk = 0; kk < 64; kk += 32) {
                int kb = kk >> 3;
                bfrag8 af[4], bfr[4];
                #pragma unroll
                for (int mi = 0; mi < 4; mi++) {
                    int R = wr + mi * 16 + l15;
                    int pc = ((kb + quad) ^ (l15 & 7)) * 8;
                    af[mi] = *(const bfrag8*)&As[R * 64 + pc];
                }
                #pragma unroll
                for (int ni = 0; ni < 4; ni++) {
                    int R = wc + ni * 16 + l15;
                    int pc = ((kb + quad) ^ (l15 & 7)) * 8;
                    bfr[ni] = *(const bfrag8*)&Bs[R * 64 + pc];
                }
                #pragma unroll
                for (int mi = 0; mi < 4; mi++)
                    #pragma unroll
                    for (int ni = 0; ni < 4; ni++)
                        acc[mi][ni] = mfma16(af[mi], bfr[ni], acc[mi][ni]);
            }
            __syncthreads();
        }
        constexpr float invtau = 1.0f / TAU;
        float rs[4][4];
        float cs[4] = {0.f, 0.f, 0.f, 0.f};
        #pragma unroll
        for (int mi = 0; mi < 4; mi++)
            #pragma unroll
            for (int r = 0; r < 4; r++) rs[mi][r] = 0.f;
        #pragma unroll
        for (int mi = 0; mi < 4; mi++)
            #pragma unroll
            for (int ni = 0; ni < 4; ni++)
                #pragma unroll
                for (int r = 0; r < 4; r++) {
                    float e = __expf(acc[mi][ni][r] * invtau);
                    rs[mi][r] += e;
                    cs[ni] += e;
                }
        #pragma unroll
        for (int mi = 0; mi < 4; mi++)
            #pragma unroll
            for (int r = 0; r < 4; r++) {
                float v = rs[mi][r];
                v += __shfl_xor(v, 1); v += __shfl_xor(v, 2);
                v += __shfl_xor(v, 4); v += __shfl_xor(v, 8);
                rs[mi][r] = v;
            }
        if (l15 == 0) {
            #pragma unroll
            for (int mi = 0; mi < 4; mi++)
                #pragma unroll
                for (int r = 0; r < 4; r++)
                    atomicAdd(&rowsum[(size_t)pair * N + bm + wr + mi * 16 + quad * 4 + r], rs[mi][r]);
        }
        #pragma unroll
        for (int ni = 0; ni < 4; ni++) {
            float v = cs[ni];
            v += __shfl_xor(v, 16); v += __shfl_xor(v, 32);
            if (quad == 0)
                atomicAdd(&colsum[(size_t)pair * N + bn + wc + ni * 16 + l15], v);
        }
    } else if (y < 64) {
        // ---- posdot for 4 nodes (one per wave)
        int wave = threadIdx.x >> 6, lane = threadIdx.x & 63;
        int nb = blockIdx.x * 32 + (y - 32);    // [0,1024)
        int n = nb * 4 + wave;
        const __hip_bfloat16* Qa = q + (size_t)pair * N * D;
        const __hip_bfloat16* Qb = q + (size_t)2 * N * D;
        int dg = deg[pair * N + n];
        int idxv = 0; float valv = 0.f;
        if (lane < MAXDEG) {
            idxv = nbr_idx[((size_t)pair * N + n) * MAXDEG + lane];
            valv = nbr_val[((size_t)pair * N + n) * MAXDEG + lane];
        }
        const float invtau = 1.0f / TAU;
        ushort4 ar = *(const ushort4*)&Qa[(size_t)n * D + lane * 4];
        ushort4 br = *(const ushort4*)&Qb[(size_t)n * D + lane * 4];
        float a[4] = {bfbits2f(ar.x), bfbits2f(ar.y), bfbits2f(ar.z), bfbits2f(ar.w)};
        float b[4] = {bfbits2f(br.x), bfbits2f(br.y), bfbits2f(br.z), bfbits2f(br.w)};
        float sr = 0.f, sc = 0.f;
        int k = 0;
        for (; k + 1 < dg; k += 2) {
            int j0 = __shfl(idxv, k), j1 = __shfl(idxv, k + 1);
            float vk0 = __shfl(valv, k), vk1 = __shfl(valv, k + 1);
            ushort4 pj0 = *(const ushort4*)&Qb[(size_t)j0 * D + lane * 4];
            ushort4 aj0 = *(const ushort4*)&Qa[(size_t)j0 * D + lane * 4];
            ushort4 pj1 = *(const ushort4*)&Qb[(size_t)j1 * D + lane * 4];
            ushort4 aj1 = *(const ushort4*)&Qa[(size_t)j1 * D + lane * 4];
            float dr0 = a[0] * bfbits2f(pj0.x) + a[1] * bfbits2f(pj0.y) +
                        a[2] * bfbits2f(pj0.z) + a[3] * bfbits2f(pj0.w);
            float dc0 = b[0] * bfbits2f(aj0.x) + b[1] * bfbits2f(aj0.y) +
                        b[2] * bfbits2f(aj0.z) + b[3] * bfbits2f(aj0.w);
            float dr1 = a[0] * bfbits2f(pj1.x) + a[1] * bfbits2f(pj1.y) +
                        a[2] * bfbits2f(pj1.z) + a[3] * bfbits2f(pj1.w);
            float dc1 = b[0] * bfbits2f(aj1.x) + b[1] * bfbits2f(aj1.y) +
                        b[2] * bfbits2f(aj1.z) + b[3] * bfbits2f(aj1.w);
            #pragma unroll
            for (int s2 = 1; s2 <= 32; s2 <<= 1) {
                dr0 += __shfl_xor(dr0, s2); dc0 += __shfl_xor(dc0, s2);
                dr1 += __shfl_xor(dr1, s2); dc1 += __shfl_xor(dc1, s2);
            }
            sr += __expf(dr0 * invtau) * vk0 + __expf(dr1 * invtau) * vk1;
            sc += __expf(dc0 * invtau) * vk0 + __expf(dc1 * invtau) * vk1;
        }
        if (k < dg) {
            int j = __shfl(idxv, k);
            float vk = __shfl(valv, k);
            ushort4 pj = *(const ushort4*)&Qb[(size_t)j * D + lane * 4];
            ushort4 aj = *(const ushort4*)&Qa[(size_t)j * D + lane * 4];
            float dr = a[0] * bfbits2f(pj.x) + a[1] * bfbits2f(pj.y) +
                       a[2] * bfbits2f(pj.z) + a[3] * bfbits2f(pj.w);
            float dc = b[0] * bfbits2f(aj.x) + b[1] * bfbits2f(aj.y) +
                       b[2] * bfbits2f(aj.z) + b[3] * bfbits2f(aj.w);
            #pragma unroll
            for (int s2 = 1; s2 <= 32; s2 <<= 1) { dr += __shfl_xor(dr, s2); dc += __shfl_xor(dc, s2); }
            sr += __expf(dr * invtau) * vk;
            sc += __expf(dc * invtau) * vk;
        }
        if (lane == 0) { pdrow[pair * N + n] = sr; pdcol[pair * N + n] = sc; }
    } else {
        // ---- beta (redundant reduce per block) + z_mp output slice
        int bf = get_bf(counter);
        int t = threadIdx.x;
        float* red = (float*)As;     // alias LDS
        float* w   = (float*)Bs;
        for (int p = 0; p < P; p++) {
            float v = (spacc[p * D + t] / (float)N) * b2f(conv[OFF_AV + t]);
            red[t] = v;
            __syncthreads();
            for (int s = 128; s > 0; s >>= 1) { if (t < s) red[t] += red[t + s]; __syncthreads(); }
            if (t == 0) w[p] = red[0];
            __syncthreads();
        }
        float m = fmaxf(w[0], fmaxf(w[1], w[2]));
        float e0 = __expf(w[0] - m), e1 = __expf(w[1] - m), e2 = __expf(w[2] - m);
        float ssum = e0 + e1 + e2;
        float b0 = e0 / ssum, b1 = e1 / ssum, b2 = e2 / ssum;
        int slice = pair * 32 + blockIdx.x;       // [0,64)
        int base = slice * (N * D / 64);
        for (int e = t * 4; e < N * D / 64; e += 256 * 4) {
            int i = base + e;
            ushort4 x0 = *(const ushort4*)&embBase[i];
            ushort4 x1 = *(const ushort4*)&embBase[(size_t)N * D + i];
            ushort4 x2 = *(const ushort4*)&embBase[(size_t)2 * N * D + i];
            float v[4];
            v[0] = b0 * bfbits2f(x0.x) + b1 * bfbits2f(x1.x) + b2 * bfbits2f(x2.x);
            v[1] = b0 * bfbits2f(x0.y) + b1 * bfbits2f(x1.y) + b2 * bfbits2f(x2.y);
            v[2] = b0 * bfbits2f(x0.z) + b1 * bfbits2f(x1.z) + b2 * bfbits2f(x2.z);
            v[3] = b0 * bfbits2f(x0.w) + b1 * bfbits2f(x1.w) + b2 * bfbits2f(x2.w);
            if (bf) {
                ushort4 ov;
                ov.x = f2bfbits(v[0]); ov.y = f2bfbits(v[1]);
                ov.z = f2bfbits(v[2]); ov.w = f2bfbits(v[3]);
                *(ushort4*)&((__hip_bfloat16*)out)[i] = ov;
            } else {
                float* o = (float*)out;
                o[i] = v[0]; o[i + 1] = v[1]; o[i + 2] = v[2]; o[i + 3] = v[3];
            }
        }
    }
}

// ---------------------------------------------------------------------------
// 6. finalize: 32 blocks, atomic merge; last block writes loss to out[N*D].
// ---------------------------------------------------------------------------
__global__ void __launch_bounds__(256)
finalize_loss(const float* __restrict__ nlpart,
              const float* __restrict__ rowsum, const float* __restrict__ colsum,
              const float* __restrict__ pdrow, const float* __restrict__ pdcol,
              const int* __restrict__ counter,
              float* __restrict__ lossacc, int* __restrict__ donecnt,
              void* __restrict__ out) {
    int bf = get_bf(counter);
    int t = threadIdx.x;
    int nb = gridDim.x;
    __shared__ float red[256];
    float s = 0.f;
    int g0 = blockIdx.x * 256 + t, gs = nb * 256;
    for (int i = g0; i < P * N; i += gs) s += nlpart[i];
    for (int i = g0; i < 2 * N; i += gs) {
        float l12 = -logf(pdrow[i] / (rowsum[i] + 1e-8f));
        float l21 = -logf(pdcol[i] / (colsum[i] + 1e-8f));
        s += (0.5f * l12 + 0.5f * l21) / (float)N;
    }
    red[t] = s;
    __syncthreads();
    for (int st = 128; st > 0; st >>= 1) { if (t < st) red[t] += red[t + st]; __syncthreads(); }
    if (t == 0) {
        atomicAdd(lossacc, red[0]);
        __threadfence();
        int d = atomicAdd(donecnt, 1);
        if (d == nb - 1) {
            float loss = atomicAdd(lossacc, 0.f);   // coherent device-scope read
            if (bf) ((__hip_bfloat16*)out)[(size_t)N * D] = __float2bfloat16(loss);
            else    ((float*)out)[(size_t)N * D] = loss;
        }
    }
}

extern "C" void kernel_launch(void* const* d_in, const int* in_sizes, int n_in,
                              void* d_out, int out_size, void* d_ws, size_t ws_size,
                              hipStream_t stream) {
    const void* h        = d_in[0];
    const void* mps      = d_in[1];
    const void* W_gcn    = d_in[2];
    const void* b_gcn    = d_in[3];
    const void* prelu_a  = d_in[4];
    const void* att_fc_W = d_in[5];
    const void* att_fc_b = d_in[6];
    const void* att_vec  = d_in[7];
    const void* proj_W1  = d_in[8];
    const void* proj_b1  = d_in[9];
    const void* proj_W2  = d_in[10];
    const void* proj_b2  = d_in[11];

    char* ws = (char*)d_ws;
    size_t off = 0;
    auto alloc = [&](size_t bytes) -> char* {
        char* p = ws + off;
        off = (off + bytes + 255) & ~(size_t)255;
        return p;
    };
    __hip_bfloat16* conv = (__hip_bfloat16*)alloc((size_t)CONV_TOTAL * 2);
    __hip_bfloat16* xbuf = (__hip_bfloat16*)alloc((size_t)P * N * D * 2);
    __hip_bfloat16* emb  = (__hip_bfloat16*)alloc((size_t)P * N * D * 2);
    __hip_bfloat16* q    = (__hip_bfloat16*)alloc((size_t)P * N * D * 2);
    int*   nbr_idx = (int*)alloc((size_t)P * N * MAXDEG * 4);
    float* nbr_val = (float*)alloc((size_t)P * N * MAXDEG * 4);
    int*   neg_idx = (int*)alloc((size_t)P * N * MAXDEG * 4);
    int*   deg     = (int*)alloc((size_t)P * N * 4);
    float* nlpart  = (float*)alloc((size_t)P * N * 4);
    float* pdrow   = (float*)alloc((size_t)2 * N * 4);
    float* pdcol   = (float*)alloc((size_t)2 * N * 4);
    char* zero_begin = ws + off;
    float* rowsum = (float*)alloc((size_t)2 * N * 4);
    float* colsum = (float*)alloc((size_t)2 * N * 4);
    float* spacc  = (float*)alloc((size_t)P * D * 4);
    float* lossacc = (float*)alloc(256);            // zeroed
    int*   donecnt = (int*)alloc(256);              // zeroed
    size_t zero_bytes = (size_t)((ws + off) - zero_begin);
    int*   counter = (int*)alloc(16);   // NOT zeroed: detect uses atomicMax sentinel

    // 0. dtype detection (1MB sample) + zero the atomic-accumulator region
    detect_dtype<<<256, 256, 0, stream>>>((const unsigned int*)mps, 256 * 1024,
                                          counter, (float*)zero_begin,
                                          (int)(zero_bytes / 4));

    // 1. fused: triple GEMM (raw h/Wg) + sparse extraction + small-weight convert
    stage2<<<256 + P * N + 64, 256, 0, stream>>>(h, W_gcn, mps,
                                                 att_fc_W, proj_W1, proj_W2, b_gcn,
                                                 att_fc_b, att_vec, prelu_a, proj_b1, proj_b2,
                                                 counter, conv, xbuf,
                                                 nbr_idx, nbr_val, neg_idx, deg);

    // 2. emb[z] = prelu(spmm + bias)
    spmm_prelu<<<dim3(N / 4, 1, P), 256, 0, stream>>>(xbuf, nbr_idx, nbr_val, deg, conv, emb);

    // 3. fused: spacc/elu GEMM + node loss
    gemm_dual_nl<<<dim3(64, 20, P), 256, 0, stream>>>(emb, conv, xbuf, spacc,
                                                      nbr_idx, neg_idx, deg, nlpart);

    // 4. q[z] = rownorm(xbuf[z] @ W2^T + b2), fused
    gemm_w2_norm<<<dim3(N / 16, 1, P), 256, 0, stream>>>(xbuf, conv, q);

    // 5. fused: sim rowsum/colsum + posdot + beta/z_mp output
    sim_pd_zmp<<<dim3(32, 65, 2), 256, 0, stream>>>(q, rowsum, colsum, emb,
                                                    nbr_idx, nbr_val, deg,
                                                    pdrow, pdcol, spacc, conv,
                                                    counter, d_out);

    // 6. finalize: parallel loss reduce (32 blocks, atomic merge)
    finalize_loss<<<32, 256, 0, stream>>>(nlpart, rowsum, colsum, pdrow, pdcol,
                                          counter, lossacc, donecnt, d_out);
}